// Round 2
// baseline (1468.873 us; speedup 1.0000x reference)
//
#include <hip/hip_runtime.h>
#include <hip/hip_fp16.h>

typedef _Float16 f16;
typedef _Float16 f16x4 __attribute__((ext_vector_type(4)));
typedef _Float16 f16x8 __attribute__((ext_vector_type(8)));
typedef float f32x4 __attribute__((ext_vector_type(4)));

#define B_SZ   4096
#define T_SZ   32
#define VOCAB  10000
#define E_SZ   300
#define H_SZ   300
#define KP     320          // embT row width (10x32)
#define GP     304          // per-gate padded N (19x16)
#define G4     1216         // 4*GP
#define LDA    328          // hbuf row stride f16
#define LDG    1224         // kR8 gates row stride f16
#define R14    32           // rows per block for kR14
#define NB14   (B_SZ/R14)   // 128 blocks -> halved L2 weight streaming

__device__ __forceinline__ float sigmoid_f(float x) {
    return 1.f / (1.f + __expf(-x));
}
__device__ __forceinline__ float tanh_f(float x) {
    return 2.f / (1.f + __expf(-2.f * x)) - 1.f;
}

// P0: embed_w f32 [V][300] -> embT f16 [V][320] zero-padded
__global__ void kP0(const float* __restrict__ ew, f16* __restrict__ embT) {
    int v = blockIdx.x, k = threadIdx.x;           // 320 threads
    embT[(size_t)v * KP + k] = (k < E_SZ) ? (f16)ew[(size_t)v * E_SZ + k] : (f16)0.f;
}

// kPW2: fused-stream packing (for kX2 / kR8): block (gate,nt,k20), 1 KB each.
__global__ void kPW2(const float* __restrict__ wih, const float* __restrict__ whh,
                     const float* __restrict__ bih, const float* __restrict__ bhh,
                     f16* __restrict__ Wpk, float* __restrict__ biasp) {
    int bid = blockIdx.x;                          // 0..1519 = (gate*19+nt)*20+k
    int lane = threadIdx.x;                        // 64
    int k = bid % 20, ntg = bid / 20;
    int nt = ntg % 19, gate = ntg / 19;
    int c = lane & 15, q = lane >> 4;
    int j = nt * 16 + c;
    int src = gate * H_SZ + j;
    f16 vals[8];
#pragma unroll
    for (int jj = 0; jj < 8; ++jj) {
        int kk = k * 32 + q * 8 + jj;
        float v = 0.f;
        if (j < H_SZ) {
            if (kk < KP) { if (kk < H_SZ) v = whh[(size_t)src * H_SZ + kk]; }
            else { int kx = kk - KP; if (kx < E_SZ) v = wih[(size_t)src * E_SZ + kx]; }
        }
        vals[jj] = (f16)v;
    }
    *(f16x8*)(Wpk + ((size_t)bid * 64 + lane) * 8) = *(const f16x8*)vals;
    if (k == 0 && q == 0)
        biasp[gate * GP + j] = (j < H_SZ) ? (bih[src] + bhh[src]) : 0.f;
}

// kPW4: gate-major W_hh-only packing: block (nt, gate, k10), 1 KB each.
// 800 blocks (760 real + 40 zero slack).
__global__ void kPW4(const float* __restrict__ whh, f16* __restrict__ WgS) {
    int bid = blockIdx.x;                          // 0..799
    int lane = threadIdx.x;
    int c = lane & 15, q = lane >> 4;
    f16 vals[8];
    if (bid < 760) {
        int nt = bid / 40, g = (bid % 40) / 10, k = bid % 10;
        int j = nt * 16 + c;
        int src = g * H_SZ + j;
#pragma unroll
        for (int jj = 0; jj < 8; ++jj) {
            int kk = k * 32 + q * 8 + jj;
            float v = (j < H_SZ && kk < H_SZ) ? whh[(size_t)src * H_SZ + kk] : 0.f;
            vals[jj] = (f16)v;
        }
    } else {
#pragma unroll
        for (int jj = 0; jj < 8; ++jj) vals[jj] = (f16)0.f;
    }
    *(f16x8*)(WgS + ((size_t)bid * 64 + lane) * 8) = *(const f16x8*)vals;
}

// P2: weight-normed classifier W = g * v / ||v||  -> Wc f32 [2][GP]
__global__ void kP2(const float* __restrict__ cls_v, const float* __restrict__ cls_g,
                    float* __restrict__ Wc) {
    int lane = threadIdx.x;
    for (int cl = 0; cl < 2; ++cl) {
        float s = 0.f;
        for (int j = lane; j < H_SZ; j += 64) { float v = cls_v[cl * H_SZ + j]; s += v * v; }
        for (int off = 32; off; off >>= 1) s += __shfl_down(s, off);
        float nrm = sqrtf(__shfl(s, 0));
        float scale = cls_g[cl] / nrm;
        for (int j = lane; j < H_SZ; j += 64) Wc[cl * GP + j] = cls_v[cl * H_SZ + j] * scale;
    }
}

// kX2: per-vocab x-gate preacts, gate-interleaved f16:
// embX[v][j][gate] = (W_ih . emb[v] + b_ih + b_hh)[gate*300+j]   (row = 2432 B)
__global__ __launch_bounds__(512, 2)
void kX2(const f16* __restrict__ embT, const f16* __restrict__ Wpk,
         const float* __restrict__ biasp, f16* __restrict__ embX) {
    int tid = threadIdx.x;
    int v0 = blockIdx.x * 16;
    int wave = tid >> 6, lane = tid & 63;
    int c = lane & 15, q = lane >> 4;
    int gate = wave >> 1, half = wave & 1;
    int nt0 = half * 10, ntiles = half ? 9 : 10;
    const f16* wp0 = Wpk + (((size_t)(gate * 19 + nt0) * 20 + 10) * 64 + lane) * 8;
    f16x8 afr[10];
    const f16* arow = embT + (size_t)(v0 + c) * KP + q * 8;
#pragma unroll
    for (int k = 0; k < 10; ++k)
        afr[k] = *(const f16x8*)(arow + k * 32);
    f16x8 buf[10];
#pragma unroll
    for (int s = 0; s < 10; ++s)
        buf[s] = *(const f16x8*)(wp0 + (size_t)s * 512);
#pragma unroll 1
    for (int nt = 0; nt < ntiles - 1; ++nt) {
        int jcol = (nt0 + nt) * 16 + c;
        float bia = biasp[gate * GP + jcol];
        f32x4 acc = {bia, bia, bia, bia};
#pragma unroll
        for (int k = 0; k < 10; ++k) {
            acc = __builtin_amdgcn_mfma_f32_16x16x32_f16(afr[k], buf[k], acc, 0, 0, 0);
            buf[k] = *(const f16x8*)(wp0 + (size_t)(nt * 20 + k + 20) * 512);
        }
#pragma unroll
        for (int r = 0; r < 4; ++r)
            embX[((size_t)(v0 + q * 4 + r) * GP + jcol) * 4 + gate] = (f16)acc[r];
    }
    {
        int nt = ntiles - 1;
        int jcol = (nt0 + nt) * 16 + c;
        float bia = biasp[gate * GP + jcol];
        f32x4 acc = {bia, bia, bia, bia};
#pragma unroll
        for (int k = 0; k < 10; ++k)
            acc = __builtin_amdgcn_mfma_f32_16x16x32_f16(afr[k], buf[k], acc, 0, 0, 0);
#pragma unroll
        for (int r = 0; r < 4; ++r)
            embX[((size_t)(v0 + q * 4 + r) * GP + jcol) * 4 + gate] = (f16)acc[r];
    }
}

// kR14: 32 rows/block (128 blocks). Each weight chunk streamed from L2 feeds TWO
// 16-row MFMAs -> chip-wide weight traffic halves vs kR13 (the measured bottleneck:
// 195 MB/step @ 18.5 TB/s L2). c-state in registers; x-preacts prefetched per-tile
// straight into VGPRs (gather latency hides under the 80-MFMA tile loop); gate-3
// prefetch wraps to next step's tile0/gate0 so no fill is wasted and no step-start
// weight reload phase exists. LDS 46 KB, one barrier per step.
__global__ __launch_bounds__(512, 2)
void kR14(const int* __restrict__ cap,
          const int* __restrict__ cap_len,
          const f16* __restrict__ embX,
          const f16* __restrict__ WgS,
          float* __restrict__ hlast) {
    __shared__ __align__(16) f16 hbufA[2 * R14 * LDA];   // 41984 B
    __shared__ int capv[R14 * T_SZ];                     // 4096 B
    __shared__ int lens[R14];                            // 128 B
    int tid = threadIdx.x;
    int b0 = blockIdx.x * R14;
    if (tid < R14) lens[tid] = cap_len[b0 + tid];
    for (int i = tid; i < R14 * T_SZ; i += 512) capv[i] = cap[(size_t)b0 * T_SZ + i];
    for (int i = tid; i < 2 * R14 * LDA; i += 512) hbufA[i] = (f16)0.f;
    __syncthreads();

    int wave = tid >> 6, lane = tid & 63;
    int c = lane & 15, q = lane >> 4;
    int tstart = (wave < 5) ? 2 * wave : 10 + 3 * (wave - 5);   // 19 = 5x2 + 3x3
    int tcnt   = (wave < 5) ? 2 : 3;
    const f16* wp0 = WgS + ((size_t)(tstart * 40) * 64 + lane) * 8;
    int tstop[2][4];
#pragma unroll
    for (int rt = 0; rt < 2; ++rt)
#pragma unroll
        for (int r = 0; r < 4; ++r) tstop[rt][r] = lens[rt * 16 + q * 4 + r] - 1;
    float creg[3][2][4];
#pragma unroll
    for (int nt = 0; nt < 3; ++nt)
#pragma unroll
        for (int rt = 0; rt < 2; ++rt)
#pragma unroll
            for (int r = 0; r < 4; ++r) creg[nt][rt][r] = 0.f;
    int cur = 0;

    // prologue: weights for this wave's tile0/gate0 (kept resident across steps
    // via the wrap-around prefetch at each tile's gate-3 loop)
    f16x8 buf[10];
#pragma unroll
    for (int s = 0; s < 10; ++s)
        buf[s] = *(const f16x8*)(wp0 + (size_t)s * 512);

    for (int t = 0; t < T_SZ; ++t) {
        const f16* hb = hbufA + cur * (R14 * LDA);
        f16*       hn = hbufA + (cur ^ 1) * (R14 * LDA);
        // token ids for this step (wave-local rows)
        int vr[2][4];
#pragma unroll
        for (int rt = 0; rt < 2; ++rt)
#pragma unroll
            for (int r = 0; r < 4; ++r)
                vr[rt][r] = capv[(rt * 16 + q * 4 + r) * T_SZ + t];
        // A fragments for both row-tiles
        f16x8 afr0[10], afr1[10];
#pragma unroll
        for (int k = 0; k < 10; ++k) {
            afr0[k] = *(const f16x8*)(hb + c * LDA + k * 32 + q * 8);
            afr1[k] = *(const f16x8*)(hb + (16 + c) * LDA + k * 32 + q * 8);
        }
#pragma unroll
        for (int nt = 0; nt < 3; ++nt) {
            if (nt < tcnt) {
                int col = (tstart + nt) * 16 + c;
                // x-preact prefetch: issued before the MFMA block, consumed after it
                f16x4 xi0[4], xi1[4];
#pragma unroll
                for (int r = 0; r < 4; ++r) {
                    xi0[r] = *(const f16x4*)(embX + (size_t)vr[0][r] * G4 + col * 4);
                    xi1[r] = *(const f16x4*)(embX + (size_t)vr[1][r] * G4 + col * 4);
                }
                f32x4 ac[4][2];
#pragma unroll
                for (int g = 0; g < 4; ++g) {
                    ac[g][0] = (f32x4){0.f, 0.f, 0.f, 0.f};
                    ac[g][1] = (f32x4){0.f, 0.f, 0.f, 0.f};
                }
#pragma unroll
                for (int g = 0; g < 4; ++g) {
                    // prefetch target: next gate of this tile; at gate 3 wrap to
                    // next tile's gate 0, or this wave's tile0/gate0 for next step
                    int nb = (g < 3) ? (nt * 40 + (g + 1) * 10)
                                     : ((nt + 1 < tcnt) ? (nt + 1) * 40 : 0);
#pragma unroll
                    for (int k = 0; k < 10; ++k) {
                        ac[g][0] = __builtin_amdgcn_mfma_f32_16x16x32_f16(afr0[k], buf[k], ac[g][0], 0, 0, 0);
                        ac[g][1] = __builtin_amdgcn_mfma_f32_16x16x32_f16(afr1[k], buf[k], ac[g][1], 0, 0, 0);
                        buf[k] = *(const f16x8*)(wp0 + (size_t)(nb + k) * 512);
                    }
                }
                // cell update: rows rt*16 + q*4 + r, column col
#pragma unroll
                for (int rt = 0; rt < 2; ++rt)
#pragma unroll
                    for (int r = 0; r < 4; ++r) {
                        f16x4 xv = rt ? xi1[r] : xi0[r];
                        float gi = ac[0][rt][r] + (float)xv[0];
                        float gf = ac[1][rt][r] + (float)xv[1];
                        float gg = ac[2][rt][r] + (float)xv[2];
                        float go = ac[3][rt][r] + (float)xv[3];
                        float ii = sigmoid_f(gi);
                        float ff = sigmoid_f(gf);
                        float gt = tanh_f(gg);
                        float oo = sigmoid_f(go);
                        float cn = ff * creg[nt][rt][r] + ii * gt;
                        creg[nt][rt][r] = cn;
                        float hh = oo * tanh_f(cn);
                        int row = rt * 16 + q * 4 + r;
                        hn[row * LDA + col] = (f16)hh;
                        if (t == tstop[rt][r])
                            hlast[(size_t)(b0 + row) * GP + col] = hh;
                    }
            }
        }
        __syncthreads();
        cur ^= 1;
    }
}

// kR8 (fallback, proven): fused [h|x] recurrence for small-ws runs.
__global__ __launch_bounds__(512, 2)
void kR8(const int* __restrict__ cap,
         const int* __restrict__ cap_len,
         const f16* __restrict__ embT,
         const f16* __restrict__ Wpk,
         const float* __restrict__ biasp,
         float* __restrict__ hlast) {
    extern __shared__ __align__(16) char smem[];
    f16*   hbuf  = (f16*)smem;                          // 10496
    f16*   xbuf  = (f16*)(smem + 10496);                // 10496
    f16*   gates = (f16*)(smem + 20992);                // 39168
    float* biasL = (float*)(smem + 60160);              // 4864
    int*   capv  = (int*)(smem + 65024);                // 2048
    int*   lens  = (int*)(smem + 67072);                // 64
    int tid = threadIdx.x;
    int b0 = blockIdx.x * 16;
    if (tid < 16) lens[tid] = cap_len[b0 + tid];
    for (int i = tid; i < 16 * T_SZ; i += 512) capv[i] = cap[(size_t)b0 * T_SZ + i];
    for (int i = tid; i < 16 * LDA; i += 512) hbuf[i] = (f16)0.f;
    for (int i = tid; i < G4; i += 512) biasL[i] = biasp[i];
    __syncthreads();
    for (int i = tid; i < 16 * 40; i += 512) {
        int m = i / 40, c8 = i - m * 40;
        int v = capv[m * T_SZ + 0];
        *(f16x8*)(xbuf + m * LDA + c8 * 8) = *(const f16x8*)(embT + (size_t)v * KP + c8 * 8);
    }
    __syncthreads();
    int wave = tid >> 6, lane = tid & 63;
    int c = lane & 15, q = lane >> 4;
    int gate = wave >> 1, half = wave & 1;
    int nt0 = half * 10, ntiles = half ? 9 : 10;
    const f16* wp0 = Wpk + ((size_t)((gate * 19 + nt0) * 20) * 64 + lane) * 8;
    const f16* hrow = hbuf + c * LDA + q * 8;
    const f16* xrow = xbuf + c * LDA + q * 8;
    float creg[10];
#pragma unroll
    for (int i = 0; i < 10; ++i) creg[i] = 0.f;

    for (int t = 0; t < T_SZ; ++t) {
        f16x8 afr[10];
#pragma unroll
        for (int k = 0; k < 10; ++k)
            afr[k] = *(const f16x8*)(hrow + k * 32);
        f16x8 buf[10];
#pragma unroll
        for (int s = 0; s < 10; ++s)
            buf[s] = *(const f16x8*)(wp0 + (size_t)s * 512);
#pragma unroll 1
        for (int nt = 0; nt < ntiles - 1; ++nt) {
            int base = nt * 20;
            int ncol = gate * GP + (nt0 + nt) * 16 + c;
            float bia = biasL[ncol];
            f32x4 acch = {bia, bia, bia, bia};
            f32x4 accx = {0.f, 0.f, 0.f, 0.f};
#pragma unroll
            for (int k = 0; k < 20; ++k) {
                if (k < 10) {
                    acch = __builtin_amdgcn_mfma_f32_16x16x32_f16(afr[k], buf[k % 10], acch, 0, 0, 0);
                } else {
                    f16x8 a = *(const f16x8*)(xrow + (k - 10) * 32);
                    accx = __builtin_amdgcn_mfma_f32_16x16x32_f16(a, buf[k % 10], accx, 0, 0, 0);
                }
                buf[k % 10] = *(const f16x8*)(wp0 + (size_t)(base + k + 10) * 512);
            }
#pragma unroll
            for (int r = 0; r < 4; ++r)
                gates[(q * 4 + r) * LDG + ncol] = (f16)(acch[r] + accx[r]);
        }
        {
            int nt = ntiles - 1;
            int base = nt * 20;
            int ncol = gate * GP + (nt0 + nt) * 16 + c;
            float bia = biasL[ncol];
            f32x4 acch = {bia, bia, bia, bia};
            f32x4 accx = {0.f, 0.f, 0.f, 0.f};
#pragma unroll
            for (int k = 0; k < 20; ++k) {
                if (k < 10) {
                    acch = __builtin_amdgcn_mfma_f32_16x16x32_f16(afr[k], buf[k % 10], acch, 0, 0, 0);
                    buf[k % 10] = *(const f16x8*)(wp0 + (size_t)(base + k + 10) * 512);
                } else {
                    f16x8 a = *(const f16x8*)(xrow + (k - 10) * 32);
                    accx = __builtin_amdgcn_mfma_f32_16x16x32_f16(a, buf[k % 10], accx, 0, 0, 0);
                }
            }
#pragma unroll
            for (int r = 0; r < 4; ++r)
                gates[(q * 4 + r) * LDG + ncol] = (f16)(acch[r] + accx[r]);
        }
        __syncthreads();
        int tp1 = t + 1;
        if (tp1 < T_SZ) {
            for (int i = tid; i < 16 * 40; i += 512) {
                int m = i / 40, c8 = i - m * 40;
                int v = capv[m * T_SZ + tp1];
                *(f16x8*)(xbuf + m * LDA + c8 * 8) =
                    *(const f16x8*)(embT + (size_t)v * KP + c8 * 8);
            }
        }
#pragma unroll
        for (int it = 0; it < 10; ++it) {
            int idx = tid + it * 512;
            int m = idx / 320, j = idx - m * 320;
            if (j < H_SZ) {
                const f16* gr = gates + m * LDG;
                float gi = (float)gr[j];
                float gf = (float)gr[GP + j];
                float gg = (float)gr[2 * GP + j];
                float go = (float)gr[3 * GP + j];
                float ii = sigmoid_f(gi);
                float ff = sigmoid_f(gf);
                float gt = tanh_f(gg);
                float oo = sigmoid_f(go);
                float cn = ff * creg[it] + ii * gt;
                creg[it] = cn;
                float hh = oo * tanh_f(cn);
                hbuf[m * LDA + j] = (f16)hh;
                if (t == lens[m] - 1) hlast[(size_t)(b0 + m) * GP + j] = hh;
            }
        }
        __syncthreads();
    }
}

// kC: out[row][cl] = hlast[row] . Wc[cl] + cls_b[cl]
__global__ void kC(const float* __restrict__ hlast, const float* __restrict__ Wc,
                   const float* __restrict__ cls_b, float* __restrict__ out) {
    int row = blockIdx.x, lane = threadIdx.x;
    const float* h = hlast + (size_t)row * GP;
    float s0 = 0.f, s1 = 0.f;
    for (int j = lane; j < H_SZ; j += 64) {
        float hv = h[j];
        s0 += hv * Wc[j];
        s1 += hv * Wc[GP + j];
    }
    for (int off = 32; off; off >>= 1) {
        s0 += __shfl_down(s0, off);
        s1 += __shfl_down(s1, off);
    }
    if (lane == 0) {
        out[row * 2 + 0] = s0 + cls_b[0];
        out[row * 2 + 1] = s1 + cls_b[1];
    }
}

extern "C" void kernel_launch(void* const* d_in, const int* in_sizes, int n_in,
                              void* d_out, int out_size, void* d_ws, size_t ws_size,
                              hipStream_t stream) {
    const int*   cap     = (const int*)d_in[0];
    const int*   cap_len = (const int*)d_in[1];
    const float* embed_w = (const float*)d_in[2];
    const float* W_ih    = (const float*)d_in[3];
    const float* W_hh    = (const float*)d_in[4];
    const float* b_ih    = (const float*)d_in[5];
    const float* b_hh    = (const float*)d_in[6];
    const float* cls_v   = (const float*)d_in[7];
    const float* cls_g   = (const float*)d_in[8];
    const float* cls_b   = (const float*)d_in[9];
    float* out = (float*)d_out;

    char* w = (char*)d_ws;
    size_t off = 0;
    auto alloc = [&](size_t bytes) -> void* {
        void* p = w + off;
        off += (bytes + 255) & ~(size_t)255;
        return p;
    };
    f16*   embT  = (f16*)alloc((size_t)VOCAB * KP * sizeof(f16));      // 6.4 MB
    f16*   Wpk   = (f16*)alloc((size_t)1520 * 64 * 8 * sizeof(f16));   // 1.56 MB
    f16*   WgS   = (f16*)alloc((size_t)800 * 64 * 8 * sizeof(f16));    // 819 KB
    float* biasp = (float*)alloc((size_t)G4 * sizeof(float));
    float* Wc    = (float*)alloc((size_t)2 * GP * sizeof(float));
    float* hlast = (float*)alloc((size_t)B_SZ * GP * sizeof(float));   // 5.0 MB
    f16*   embX  = (f16*)(w + off);                                    // 24.3 MB f16 [V][GP][4]
    size_t need_split = off + ((size_t)VOCAB * GP * 4 * sizeof(f16) + 255);
    bool split = (ws_size >= need_split);          // deterministic per run

    kP0<<<VOCAB, KP, 0, stream>>>(embed_w, embT);
    kPW2<<<1520, 64, 0, stream>>>(W_ih, W_hh, b_ih, b_hh, Wpk, biasp);
    kP2<<<1, 64, 0, stream>>>(cls_v, cls_g, Wc);
    if (split) {
        kPW4<<<800, 64, 0, stream>>>(W_hh, WgS);
        kX2<<<VOCAB / 16, 512, 0, stream>>>(embT, Wpk, biasp, embX);
        kR14<<<NB14, 512, 0, stream>>>(cap, cap_len, embX, WgS, hlast);
    } else {
        static const int smem_r8 = 67072 + 64;
        (void)hipFuncSetAttribute((const void*)kR8,
                                  hipFuncAttributeMaxDynamicSharedMemorySize, smem_r8);
        kR8<<<B_SZ / 16, 512, smem_r8, stream>>>(cap, cap_len, embT, Wpk, biasp, hlast);
    }
    kC<<<B_SZ, 64, 0, stream>>>(hlast, Wc, cls_b, out);
}

// Round 3
// 1440.902 us; speedup vs baseline: 1.0194x; 1.0194x over previous
//
#include <hip/hip_runtime.h>
#include <hip/hip_fp16.h>

typedef _Float16 f16;
typedef _Float16 f16x4 __attribute__((ext_vector_type(4)));
typedef _Float16 f16x8 __attribute__((ext_vector_type(8)));
typedef float f32x4 __attribute__((ext_vector_type(4)));

#define B_SZ   4096
#define T_SZ   32
#define VOCAB  10000
#define E_SZ   300
#define H_SZ   300
#define KP     320          // embT row width (10x32)
#define GP     304          // per-gate padded N (19x16)
#define G4     1216         // 4*GP
#define LDA    328          // hbuf row stride f16
#define LDG    1224         // kR8 gates row stride f16
#define LDC    308          // cbuf row stride f32
#define R14    32           // rows per block for kR15
#define NB14   (B_SZ/R14)   // 128 blocks

__device__ __forceinline__ float sigmoid_f(float x) {
    return 1.f / (1.f + __expf(-x));
}
__device__ __forceinline__ float tanh_f(float x) {
    return 2.f / (1.f + __expf(-2.f * x)) - 1.f;
}

// P0: embed_w f32 [V][300] -> embT f16 [V][320] zero-padded
__global__ void kP0(const float* __restrict__ ew, f16* __restrict__ embT) {
    int v = blockIdx.x, k = threadIdx.x;           // 320 threads
    embT[(size_t)v * KP + k] = (k < E_SZ) ? (f16)ew[(size_t)v * E_SZ + k] : (f16)0.f;
}

// kPW2: fused-stream packing (for kX2 / kR8): block (gate,nt,k20), 1 KB each.
__global__ void kPW2(const float* __restrict__ wih, const float* __restrict__ whh,
                     const float* __restrict__ bih, const float* __restrict__ bhh,
                     f16* __restrict__ Wpk, float* __restrict__ biasp) {
    int bid = blockIdx.x;                          // 0..1519 = (gate*19+nt)*20+k
    int lane = threadIdx.x;                        // 64
    int k = bid % 20, ntg = bid / 20;
    int nt = ntg % 19, gate = ntg / 19;
    int c = lane & 15, q = lane >> 4;
    int j = nt * 16 + c;
    int src = gate * H_SZ + j;
    f16 vals[8];
#pragma unroll
    for (int jj = 0; jj < 8; ++jj) {
        int kk = k * 32 + q * 8 + jj;
        float v = 0.f;
        if (j < H_SZ) {
            if (kk < KP) { if (kk < H_SZ) v = whh[(size_t)src * H_SZ + kk]; }
            else { int kx = kk - KP; if (kx < E_SZ) v = wih[(size_t)src * E_SZ + kx]; }
        }
        vals[jj] = (f16)v;
    }
    *(f16x8*)(Wpk + ((size_t)bid * 64 + lane) * 8) = *(const f16x8*)vals;
    if (k == 0 && q == 0)
        biasp[gate * GP + j] = (j < H_SZ) ? (bih[src] + bhh[src]) : 0.f;
}

// kPW4: gate-major W_hh-only packing: block (nt, gate, k10), 1 KB each.
// 800 blocks (760 real + 40 zero slack).
__global__ void kPW4(const float* __restrict__ whh, f16* __restrict__ WgS) {
    int bid = blockIdx.x;                          // 0..799
    int lane = threadIdx.x;
    int c = lane & 15, q = lane >> 4;
    f16 vals[8];
    if (bid < 760) {
        int nt = bid / 40, g = (bid % 40) / 10, k = bid % 10;
        int j = nt * 16 + c;
        int src = g * H_SZ + j;
#pragma unroll
        for (int jj = 0; jj < 8; ++jj) {
            int kk = k * 32 + q * 8 + jj;
            float v = (j < H_SZ && kk < H_SZ) ? whh[(size_t)src * H_SZ + kk] : 0.f;
            vals[jj] = (f16)v;
        }
    } else {
#pragma unroll
        for (int jj = 0; jj < 8; ++jj) vals[jj] = (f16)0.f;
    }
    *(f16x8*)(WgS + ((size_t)bid * 64 + lane) * 8) = *(const f16x8*)vals;
}

// P2: weight-normed classifier W = g * v / ||v||  -> Wc f32 [2][GP]
__global__ void kP2(const float* __restrict__ cls_v, const float* __restrict__ cls_g,
                    float* __restrict__ Wc) {
    int lane = threadIdx.x;
    for (int cl = 0; cl < 2; ++cl) {
        float s = 0.f;
        for (int j = lane; j < H_SZ; j += 64) { float v = cls_v[cl * H_SZ + j]; s += v * v; }
        for (int off = 32; off; off >>= 1) s += __shfl_down(s, off);
        float nrm = sqrtf(__shfl(s, 0));
        float scale = cls_g[cl] / nrm;
        for (int j = lane; j < H_SZ; j += 64) Wc[cl * GP + j] = cls_v[cl * H_SZ + j] * scale;
    }
}

// kX2: per-vocab x-gate preacts, gate-interleaved f16:
// embX[v][j][gate] = (W_ih . emb[v] + b_ih + b_hh)[gate*300+j]   (row = 2432 B)
__global__ __launch_bounds__(512, 2)
void kX2(const f16* __restrict__ embT, const f16* __restrict__ Wpk,
         const float* __restrict__ biasp, f16* __restrict__ embX) {
    int tid = threadIdx.x;
    int v0 = blockIdx.x * 16;
    int wave = tid >> 6, lane = tid & 63;
    int c = lane & 15, q = lane >> 4;
    int gate = wave >> 1, half = wave & 1;
    int nt0 = half * 10, ntiles = half ? 9 : 10;
    const f16* wp0 = Wpk + (((size_t)(gate * 19 + nt0) * 20 + 10) * 64 + lane) * 8;
    f16x8 afr[10];
    const f16* arow = embT + (size_t)(v0 + c) * KP + q * 8;
#pragma unroll
    for (int k = 0; k < 10; ++k)
        afr[k] = *(const f16x8*)(arow + k * 32);
    f16x8 buf[10];
#pragma unroll
    for (int s = 0; s < 10; ++s)
        buf[s] = *(const f16x8*)(wp0 + (size_t)s * 512);
#pragma unroll 1
    for (int nt = 0; nt < ntiles - 1; ++nt) {
        int jcol = (nt0 + nt) * 16 + c;
        float bia = biasp[gate * GP + jcol];
        f32x4 acc = {bia, bia, bia, bia};
#pragma unroll
        for (int k = 0; k < 10; ++k) {
            acc = __builtin_amdgcn_mfma_f32_16x16x32_f16(afr[k], buf[k], acc, 0, 0, 0);
            buf[k] = *(const f16x8*)(wp0 + (size_t)(nt * 20 + k + 20) * 512);
        }
#pragma unroll
        for (int r = 0; r < 4; ++r)
            embX[((size_t)(v0 + q * 4 + r) * GP + jcol) * 4 + gate] = (f16)acc[r];
    }
    {
        int nt = ntiles - 1;
        int jcol = (nt0 + nt) * 16 + c;
        float bia = biasp[gate * GP + jcol];
        f32x4 acc = {bia, bia, bia, bia};
#pragma unroll
        for (int k = 0; k < 10; ++k)
            acc = __builtin_amdgcn_mfma_f32_16x16x32_f16(afr[k], buf[k], acc, 0, 0, 0);
#pragma unroll
        for (int r = 0; r < 4; ++r)
            embX[((size_t)(v0 + q * 4 + r) * GP + jcol) * 4 + gate] = (f16)acc[r];
    }
}

// kR15: kR14's structure (32 rows/block, one weight stream -> two row-tile MFMAs)
// with the spill eliminated: waves_per_eu pinned to [2,2] so the allocator gets the
// full 256-reg/thread budget (kR14's allocator self-capped arch regs at 128 and
// spilled ~90 regs into the 32-step loop -> 170 MB scratch writes, 4x regression).
// c-state moved to LDS cbuf (saves 24 arch regs). LDS 85.6 KB dynamic, 1 block/CU.
__global__ __attribute__((amdgpu_flat_work_group_size(512, 512), amdgpu_waves_per_eu(2, 2)))
void kR15(const int* __restrict__ cap,
          const int* __restrict__ cap_len,
          const f16* __restrict__ embX,
          const f16* __restrict__ WgS,
          float* __restrict__ hlast) {
    extern __shared__ __align__(16) char smem[];
    f16*   hbufA = (f16*)smem;                           // 2*32*LDA*2 = 41984 B
    float* cbuf  = (float*)(smem + 41984);               // 32*LDC*4   = 39424 B
    int*   capv  = (int*)(smem + 81408);                 // 4096 B
    int*   lens  = (int*)(smem + 85504);                 // 128 B
    int tid = threadIdx.x;
    int b0 = blockIdx.x * R14;
    if (tid < R14) lens[tid] = cap_len[b0 + tid];
    for (int i = tid; i < R14 * T_SZ; i += 512) capv[i] = cap[(size_t)b0 * T_SZ + i];
    for (int i = tid; i < 2 * R14 * LDA; i += 512) hbufA[i] = (f16)0.f;
    for (int i = tid; i < R14 * LDC; i += 512) cbuf[i] = 0.f;
    __syncthreads();

    int wave = tid >> 6, lane = tid & 63;
    int c = lane & 15, q = lane >> 4;
    int tstart = (wave < 5) ? 2 * wave : 10 + 3 * (wave - 5);   // 19 = 5x2 + 3x3
    int tcnt   = (wave < 5) ? 2 : 3;
    const f16* wp0 = WgS + ((size_t)(tstart * 40) * 64 + lane) * 8;
    int tstop[2][4];
#pragma unroll
    for (int rt = 0; rt < 2; ++rt)
#pragma unroll
        for (int r = 0; r < 4; ++r) tstop[rt][r] = lens[rt * 16 + q * 4 + r] - 1;
    int cur = 0;

    // prologue: weights for this wave's tile0/gate0 (kept resident across steps
    // via the wrap-around prefetch at each tile's gate-3 loop)
    f16x8 buf[10];
#pragma unroll
    for (int s = 0; s < 10; ++s)
        buf[s] = *(const f16x8*)(wp0 + (size_t)s * 512);

    for (int t = 0; t < T_SZ; ++t) {
        const f16* hb = hbufA + cur * (R14 * LDA);
        f16*       hn = hbufA + (cur ^ 1) * (R14 * LDA);
        // token ids for this step (wave-local rows)
        int vr[2][4];
#pragma unroll
        for (int rt = 0; rt < 2; ++rt)
#pragma unroll
            for (int r = 0; r < 4; ++r)
                vr[rt][r] = capv[(rt * 16 + q * 4 + r) * T_SZ + t];
        // A fragments for both row-tiles
        f16x8 afr0[10], afr1[10];
#pragma unroll
        for (int k = 0; k < 10; ++k) {
            afr0[k] = *(const f16x8*)(hb + c * LDA + k * 32 + q * 8);
            afr1[k] = *(const f16x8*)(hb + (16 + c) * LDA + k * 32 + q * 8);
        }
#pragma unroll
        for (int nt = 0; nt < 3; ++nt) {
            if (nt < tcnt) {
                int col = (tstart + nt) * 16 + c;
                // x-preact prefetch: issued before the MFMA block, consumed after it
                f16x4 xi0[4], xi1[4];
#pragma unroll
                for (int r = 0; r < 4; ++r) {
                    xi0[r] = *(const f16x4*)(embX + (size_t)vr[0][r] * G4 + col * 4);
                    xi1[r] = *(const f16x4*)(embX + (size_t)vr[1][r] * G4 + col * 4);
                }
                f32x4 ac[4][2];
#pragma unroll
                for (int g = 0; g < 4; ++g) {
                    ac[g][0] = (f32x4){0.f, 0.f, 0.f, 0.f};
                    ac[g][1] = (f32x4){0.f, 0.f, 0.f, 0.f};
                }
#pragma unroll
                for (int g = 0; g < 4; ++g) {
                    // prefetch target: next gate of this tile; at gate 3 wrap to
                    // next tile's gate 0, or this wave's tile0/gate0 for next step
                    int nb = (g < 3) ? (nt * 40 + (g + 1) * 10)
                                     : ((nt + 1 < tcnt) ? (nt + 1) * 40 : 0);
#pragma unroll
                    for (int k = 0; k < 10; ++k) {
                        ac[g][0] = __builtin_amdgcn_mfma_f32_16x16x32_f16(afr0[k], buf[k], ac[g][0], 0, 0, 0);
                        ac[g][1] = __builtin_amdgcn_mfma_f32_16x16x32_f16(afr1[k], buf[k], ac[g][1], 0, 0, 0);
                        buf[k] = *(const f16x8*)(wp0 + (size_t)(nb + k) * 512);
                    }
                }
                // cell update: rows rt*16 + q*4 + r, column col
#pragma unroll
                for (int rt = 0; rt < 2; ++rt)
#pragma unroll
                    for (int r = 0; r < 4; ++r) {
                        f16x4 xv = rt ? xi1[r] : xi0[r];
                        float gi = ac[0][rt][r] + (float)xv[0];
                        float gf = ac[1][rt][r] + (float)xv[1];
                        float gg = ac[2][rt][r] + (float)xv[2];
                        float go = ac[3][rt][r] + (float)xv[3];
                        float ii = sigmoid_f(gi);
                        float ff = sigmoid_f(gf);
                        float gt = tanh_f(gg);
                        float oo = sigmoid_f(go);
                        int row = rt * 16 + q * 4 + r;
                        int ci = row * LDC + col;
                        float cn = ff * cbuf[ci] + ii * gt;
                        cbuf[ci] = cn;
                        float hh = oo * tanh_f(cn);
                        hn[row * LDA + col] = (f16)hh;
                        if (t == tstop[rt][r])
                            hlast[(size_t)(b0 + row) * GP + col] = hh;
                    }
            }
        }
        __syncthreads();
        cur ^= 1;
    }
}

// kR8 (fallback, proven): fused [h|x] recurrence for small-ws runs.
__global__ __launch_bounds__(512, 2)
void kR8(const int* __restrict__ cap,
         const int* __restrict__ cap_len,
         const f16* __restrict__ embT,
         const f16* __restrict__ Wpk,
         const float* __restrict__ biasp,
         float* __restrict__ hlast) {
    extern __shared__ __align__(16) char smem[];
    f16*   hbuf  = (f16*)smem;                          // 10496
    f16*   xbuf  = (f16*)(smem + 10496);                // 10496
    f16*   gates = (f16*)(smem + 20992);                // 39168
    float* biasL = (float*)(smem + 60160);              // 4864
    int*   capv  = (int*)(smem + 65024);                // 2048
    int*   lens  = (int*)(smem + 67072);                // 64
    int tid = threadIdx.x;
    int b0 = blockIdx.x * 16;
    if (tid < 16) lens[tid] = cap_len[b0 + tid];
    for (int i = tid; i < 16 * T_SZ; i += 512) capv[i] = cap[(size_t)b0 * T_SZ + i];
    for (int i = tid; i < 16 * LDA; i += 512) hbuf[i] = (f16)0.f;
    for (int i = tid; i < G4; i += 512) biasL[i] = biasp[i];
    __syncthreads();
    for (int i = tid; i < 16 * 40; i += 512) {
        int m = i / 40, c8 = i - m * 40;
        int v = capv[m * T_SZ + 0];
        *(f16x8*)(xbuf + m * LDA + c8 * 8) = *(const f16x8*)(embT + (size_t)v * KP + c8 * 8);
    }
    __syncthreads();
    int wave = tid >> 6, lane = tid & 63;
    int c = lane & 15, q = lane >> 4;
    int gate = wave >> 1, half = wave & 1;
    int nt0 = half * 10, ntiles = half ? 9 : 10;
    const f16* wp0 = Wpk + ((size_t)((gate * 19 + nt0) * 20) * 64 + lane) * 8;
    const f16* hrow = hbuf + c * LDA + q * 8;
    const f16* xrow = xbuf + c * LDA + q * 8;
    float creg[10];
#pragma unroll
    for (int i = 0; i < 10; ++i) creg[i] = 0.f;

    for (int t = 0; t < T_SZ; ++t) {
        f16x8 afr[10];
#pragma unroll
        for (int k = 0; k < 10; ++k)
            afr[k] = *(const f16x8*)(hrow + k * 32);
        f16x8 buf[10];
#pragma unroll
        for (int s = 0; s < 10; ++s)
            buf[s] = *(const f16x8*)(wp0 + (size_t)s * 512);
#pragma unroll 1
        for (int nt = 0; nt < ntiles - 1; ++nt) {
            int base = nt * 20;
            int ncol = gate * GP + (nt0 + nt) * 16 + c;
            float bia = biasL[ncol];
            f32x4 acch = {bia, bia, bia, bia};
            f32x4 accx = {0.f, 0.f, 0.f, 0.f};
#pragma unroll
            for (int k = 0; k < 20; ++k) {
                if (k < 10) {
                    acch = __builtin_amdgcn_mfma_f32_16x16x32_f16(afr[k], buf[k % 10], acch, 0, 0, 0);
                } else {
                    f16x8 a = *(const f16x8*)(xrow + (k - 10) * 32);
                    accx = __builtin_amdgcn_mfma_f32_16x16x32_f16(a, buf[k % 10], accx, 0, 0, 0);
                }
                buf[k % 10] = *(const f16x8*)(wp0 + (size_t)(base + k + 10) * 512);
            }
#pragma unroll
            for (int r = 0; r < 4; ++r)
                gates[(q * 4 + r) * LDG + ncol] = (f16)(acch[r] + accx[r]);
        }
        {
            int nt = ntiles - 1;
            int base = nt * 20;
            int ncol = gate * GP + (nt0 + nt) * 16 + c;
            float bia = biasL[ncol];
            f32x4 acch = {bia, bia, bia, bia};
            f32x4 accx = {0.f, 0.f, 0.f, 0.f};
#pragma unroll
            for (int k = 0; k < 20; ++k) {
                if (k < 10) {
                    acch = __builtin_amdgcn_mfma_f32_16x16x32_f16(afr[k], buf[k % 10], acch, 0, 0, 0);
                    buf[k % 10] = *(const f16x8*)(wp0 + (size_t)(base + k + 10) * 512);
                } else {
                    f16x8 a = *(const f16x8*)(xrow + (k - 10) * 32);
                    accx = __builtin_amdgcn_mfma_f32_16x16x32_f16(a, buf[k % 10], accx, 0, 0, 0);
                }
            }
#pragma unroll
            for (int r = 0; r < 4; ++r)
                gates[(q * 4 + r) * LDG + ncol] = (f16)(acch[r] + accx[r]);
        }
        __syncthreads();
        int tp1 = t + 1;
        if (tp1 < T_SZ) {
            for (int i = tid; i < 16 * 40; i += 512) {
                int m = i / 40, c8 = i - m * 40;
                int v = capv[m * T_SZ + tp1];
                *(f16x8*)(xbuf + m * LDA + c8 * 8) =
                    *(const f16x8*)(embT + (size_t)v * KP + c8 * 8);
            }
        }
#pragma unroll
        for (int it = 0; it < 10; ++it) {
            int idx = tid + it * 512;
            int m = idx / 320, j = idx - m * 320;
            if (j < H_SZ) {
                const f16* gr = gates + m * LDG;
                float gi = (float)gr[j];
                float gf = (float)gr[GP + j];
                float gg = (float)gr[2 * GP + j];
                float go = (float)gr[3 * GP + j];
                float ii = sigmoid_f(gi);
                float ff = sigmoid_f(gf);
                float gt = tanh_f(gg);
                float oo = sigmoid_f(go);
                float cn = ff * creg[it] + ii * gt;
                creg[it] = cn;
                float hh = oo * tanh_f(cn);
                hbuf[m * LDA + j] = (f16)hh;
                if (t == lens[m] - 1) hlast[(size_t)(b0 + m) * GP + j] = hh;
            }
        }
        __syncthreads();
    }
}

// kC: out[row][cl] = hlast[row] . Wc[cl] + cls_b[cl]
__global__ void kC(const float* __restrict__ hlast, const float* __restrict__ Wc,
                   const float* __restrict__ cls_b, float* __restrict__ out) {
    int row = blockIdx.x, lane = threadIdx.x;
    const float* h = hlast + (size_t)row * GP;
    float s0 = 0.f, s1 = 0.f;
    for (int j = lane; j < H_SZ; j += 64) {
        float hv = h[j];
        s0 += hv * Wc[j];
        s1 += hv * Wc[GP + j];
    }
    for (int off = 32; off; off >>= 1) {
        s0 += __shfl_down(s0, off);
        s1 += __shfl_down(s1, off);
    }
    if (lane == 0) {
        out[row * 2 + 0] = s0 + cls_b[0];
        out[row * 2 + 1] = s1 + cls_b[1];
    }
}

extern "C" void kernel_launch(void* const* d_in, const int* in_sizes, int n_in,
                              void* d_out, int out_size, void* d_ws, size_t ws_size,
                              hipStream_t stream) {
    const int*   cap     = (const int*)d_in[0];
    const int*   cap_len = (const int*)d_in[1];
    const float* embed_w = (const float*)d_in[2];
    const float* W_ih    = (const float*)d_in[3];
    const float* W_hh    = (const float*)d_in[4];
    const float* b_ih    = (const float*)d_in[5];
    const float* b_hh    = (const float*)d_in[6];
    const float* cls_v   = (const float*)d_in[7];
    const float* cls_g   = (const float*)d_in[8];
    const float* cls_b   = (const float*)d_in[9];
    float* out = (float*)d_out;

    char* w = (char*)d_ws;
    size_t off = 0;
    auto alloc = [&](size_t bytes) -> void* {
        void* p = w + off;
        off += (bytes + 255) & ~(size_t)255;
        return p;
    };
    f16*   embT  = (f16*)alloc((size_t)VOCAB * KP * sizeof(f16));      // 6.4 MB
    f16*   Wpk   = (f16*)alloc((size_t)1520 * 64 * 8 * sizeof(f16));   // 1.56 MB
    f16*   WgS   = (f16*)alloc((size_t)800 * 64 * 8 * sizeof(f16));    // 819 KB
    float* biasp = (float*)alloc((size_t)G4 * sizeof(float));
    float* Wc    = (float*)alloc((size_t)2 * GP * sizeof(float));
    float* hlast = (float*)alloc((size_t)B_SZ * GP * sizeof(float));   // 5.0 MB
    f16*   embX  = (f16*)(w + off);                                    // 24.3 MB f16 [V][GP][4]
    size_t need_split = off + ((size_t)VOCAB * GP * 4 * sizeof(f16) + 255);
    bool split = (ws_size >= need_split);          // deterministic per run

    kP0<<<VOCAB, KP, 0, stream>>>(embed_w, embT);
    kPW2<<<1520, 64, 0, stream>>>(W_ih, W_hh, b_ih, b_hh, Wpk, biasp);
    kP2<<<1, 64, 0, stream>>>(cls_v, cls_g, Wc);
    if (split) {
        kPW4<<<800, 64, 0, stream>>>(W_hh, WgS);
        kX2<<<VOCAB / 16, 512, 0, stream>>>(embT, Wpk, biasp, embX);
        static const int smem_r15 = 85632;
        (void)hipFuncSetAttribute((const void*)kR15,
                                  hipFuncAttributeMaxDynamicSharedMemorySize, smem_r15);
        kR15<<<NB14, 512, smem_r15, stream>>>(cap, cap_len, embX, WgS, hlast);
    } else {
        static const int smem_r8 = 67072 + 64;
        (void)hipFuncSetAttribute((const void*)kR8,
                                  hipFuncAttributeMaxDynamicSharedMemorySize, smem_r8);
        kR8<<<B_SZ / 16, 512, smem_r8, stream>>>(cap, cap_len, embT, Wpk, biasp, hlast);
    }
    kC<<<B_SZ, 64, 0, stream>>>(hlast, Wc, cls_b, out);
}

// Round 4
// 1225.193 us; speedup vs baseline: 1.1989x; 1.1761x over previous
//
#include <hip/hip_runtime.h>
#include <hip/hip_fp16.h>

typedef _Float16 f16;
typedef _Float16 f16x4 __attribute__((ext_vector_type(4)));
typedef _Float16 f16x8 __attribute__((ext_vector_type(8)));
typedef float f32x4 __attribute__((ext_vector_type(4)));

#define B_SZ   4096
#define T_SZ   32
#define VOCAB  10000
#define E_SZ   300
#define H_SZ   300
#define KP     320          // embT row width (10x32)
#define GP     304          // per-gate padded N (19x16)
#define G4     1216         // 4*GP
#define LDA    328          // hbuf row stride f16
#define LDG    1224         // kR8 gates row stride f16
#define LDC    308          // cbuf row stride f32
#define R14    32           // rows per block for kR16
#define NB14   (B_SZ/R14)   // 128 blocks

__device__ __forceinline__ float sigmoid_f(float x) {
    return 1.f / (1.f + __expf(-x));
}
__device__ __forceinline__ float tanh_f(float x) {
    return 2.f / (1.f + __expf(-2.f * x)) - 1.f;
}

// P0: embed_w f32 [V][300] -> embT f16 [V][320] zero-padded
__global__ void kP0(const float* __restrict__ ew, f16* __restrict__ embT) {
    int v = blockIdx.x, k = threadIdx.x;           // 320 threads
    embT[(size_t)v * KP + k] = (k < E_SZ) ? (f16)ew[(size_t)v * E_SZ + k] : (f16)0.f;
}

// kPW2: fused-stream packing (for kX2 / kR8): block (gate,nt,k20), 1 KB each.
__global__ void kPW2(const float* __restrict__ wih, const float* __restrict__ whh,
                     const float* __restrict__ bih, const float* __restrict__ bhh,
                     f16* __restrict__ Wpk, float* __restrict__ biasp) {
    int bid = blockIdx.x;                          // 0..1519 = (gate*19+nt)*20+k
    int lane = threadIdx.x;                        // 64
    int k = bid % 20, ntg = bid / 20;
    int nt = ntg % 19, gate = ntg / 19;
    int c = lane & 15, q = lane >> 4;
    int j = nt * 16 + c;
    int src = gate * H_SZ + j;
    f16 vals[8];
#pragma unroll
    for (int jj = 0; jj < 8; ++jj) {
        int kk = k * 32 + q * 8 + jj;
        float v = 0.f;
        if (j < H_SZ) {
            if (kk < KP) { if (kk < H_SZ) v = whh[(size_t)src * H_SZ + kk]; }
            else { int kx = kk - KP; if (kx < E_SZ) v = wih[(size_t)src * E_SZ + kx]; }
        }
        vals[jj] = (f16)v;
    }
    *(f16x8*)(Wpk + ((size_t)bid * 64 + lane) * 8) = *(const f16x8*)vals;
    if (k == 0 && q == 0)
        biasp[gate * GP + j] = (j < H_SZ) ? (bih[src] + bhh[src]) : 0.f;
}

// kPW4: gate-major W_hh-only packing: block (nt, gate, k10), 1 KB each.
// 800 blocks (760 real + 40 zero slack).
__global__ void kPW4(const float* __restrict__ whh, f16* __restrict__ WgS) {
    int bid = blockIdx.x;                          // 0..799
    int lane = threadIdx.x;
    int c = lane & 15, q = lane >> 4;
    f16 vals[8];
    if (bid < 760) {
        int nt = bid / 40, g = (bid % 40) / 10, k = bid % 10;
        int j = nt * 16 + c;
        int src = g * H_SZ + j;
#pragma unroll
        for (int jj = 0; jj < 8; ++jj) {
            int kk = k * 32 + q * 8 + jj;
            float v = (j < H_SZ && kk < H_SZ) ? whh[(size_t)src * H_SZ + kk] : 0.f;
            vals[jj] = (f16)v;
        }
    } else {
#pragma unroll
        for (int jj = 0; jj < 8; ++jj) vals[jj] = (f16)0.f;
    }
    *(f16x8*)(WgS + ((size_t)bid * 64 + lane) * 8) = *(const f16x8*)vals;
}

// P2: weight-normed classifier W = g * v / ||v||  -> Wc f32 [2][GP]
__global__ void kP2(const float* __restrict__ cls_v, const float* __restrict__ cls_g,
                    float* __restrict__ Wc) {
    int lane = threadIdx.x;
    for (int cl = 0; cl < 2; ++cl) {
        float s = 0.f;
        for (int j = lane; j < H_SZ; j += 64) { float v = cls_v[cl * H_SZ + j]; s += v * v; }
        for (int off = 32; off; off >>= 1) s += __shfl_down(s, off);
        float nrm = sqrtf(__shfl(s, 0));
        float scale = cls_g[cl] / nrm;
        for (int j = lane; j < H_SZ; j += 64) Wc[cl * GP + j] = cls_v[cl * H_SZ + j] * scale;
    }
}

// kX2: per-vocab x-gate preacts, gate-interleaved f16:
// embX[v][j][gate] = (W_ih . emb[v] + b_ih + b_hh)[gate*300+j]   (row = 2432 B)
__global__ __launch_bounds__(512, 2)
void kX2(const f16* __restrict__ embT, const f16* __restrict__ Wpk,
         const float* __restrict__ biasp, f16* __restrict__ embX) {
    int tid = threadIdx.x;
    int v0 = blockIdx.x * 16;
    int wave = tid >> 6, lane = tid & 63;
    int c = lane & 15, q = lane >> 4;
    int gate = wave >> 1, half = wave & 1;
    int nt0 = half * 10, ntiles = half ? 9 : 10;
    const f16* wp0 = Wpk + (((size_t)(gate * 19 + nt0) * 20 + 10) * 64 + lane) * 8;
    f16x8 afr[10];
    const f16* arow = embT + (size_t)(v0 + c) * KP + q * 8;
#pragma unroll
    for (int k = 0; k < 10; ++k)
        afr[k] = *(const f16x8*)(arow + k * 32);
    f16x8 buf[10];
#pragma unroll
    for (int s = 0; s < 10; ++s)
        buf[s] = *(const f16x8*)(wp0 + (size_t)s * 512);
#pragma unroll 1
    for (int nt = 0; nt < ntiles - 1; ++nt) {
        int jcol = (nt0 + nt) * 16 + c;
        float bia = biasp[gate * GP + jcol];
        f32x4 acc = {bia, bia, bia, bia};
#pragma unroll
        for (int k = 0; k < 10; ++k) {
            acc = __builtin_amdgcn_mfma_f32_16x16x32_f16(afr[k], buf[k], acc, 0, 0, 0);
            buf[k] = *(const f16x8*)(wp0 + (size_t)(nt * 20 + k + 20) * 512);
        }
#pragma unroll
        for (int r = 0; r < 4; ++r)
            embX[((size_t)(v0 + q * 4 + r) * GP + jcol) * 4 + gate] = (f16)acc[r];
    }
    {
        int nt = ntiles - 1;
        int jcol = (nt0 + nt) * 16 + c;
        float bia = biasp[gate * GP + jcol];
        f32x4 acc = {bia, bia, bia, bia};
#pragma unroll
        for (int k = 0; k < 10; ++k)
            acc = __builtin_amdgcn_mfma_f32_16x16x32_f16(afr[k], buf[k], acc, 0, 0, 0);
#pragma unroll
        for (int r = 0; r < 4; ++r)
            embX[((size_t)(v0 + q * 4 + r) * GP + jcol) * 4 + gate] = (f16)acc[r];
    }
}

// kR16: 32 rows/block (128 blocks), register-budget-safe restructure.
// kR14/kR15 spilled (~40 loop-carried regs -> 1.3 GB scratch reloads) because the
// allocator caps the arch side at ~128 regs for MFMA kernels. kR16 fits under that
// wall by construction: one col-tile processed to completion at a time (acc = 32),
// K split into two 5-chunk halves (afr = 40 regs, re-read per tile-half from LDS
// -- ds pipe runs parallel to MFMA), buf[5] rotating weight prefetch (20 regs).
// Arch demand ~110. Weight stream from L2 still feeds TWO 16-row MFMAs per chunk.
__global__ __launch_bounds__(512, 1)
void kR16(const int* __restrict__ cap,
          const int* __restrict__ cap_len,
          const f16* __restrict__ embX,
          const f16* __restrict__ WgS,
          float* __restrict__ hlast) {
    extern __shared__ __align__(16) char smem[];
    f16*   hbufA = (f16*)smem;                           // 2*32*LDA*2 = 41984 B
    float* cbuf  = (float*)(smem + 41984);               // 32*LDC*4   = 39424 B
    int*   capv  = (int*)(smem + 81408);                 // 4096 B
    int*   lens  = (int*)(smem + 85504);                 // 128 B
    int tid = threadIdx.x;
    int b0 = blockIdx.x * R14;
    if (tid < R14) lens[tid] = cap_len[b0 + tid];
    for (int i = tid; i < R14 * T_SZ; i += 512) capv[i] = cap[(size_t)b0 * T_SZ + i];
    for (int i = tid; i < 2 * R14 * LDA; i += 512) hbufA[i] = (f16)0.f;
    for (int i = tid; i < R14 * LDC; i += 512) cbuf[i] = 0.f;
    __syncthreads();

    int wave = tid >> 6, lane = tid & 63;
    int c = lane & 15, q = lane >> 4;
    int tstart = (wave < 5) ? 2 * wave : 10 + 3 * (wave - 5);   // 19 = 5x2 + 3x3
    int tcnt   = (wave < 5) ? 2 : 3;
    const f16* wp0 = WgS + ((size_t)(tstart * 40) * 64 + lane) * 8;
    int cur = 0;

    // weight chunk (rel to wp0): rel(nt,g,h) = nt*40 + g*10 + h*5, 5 chunks each.
    // prologue: tile0/gate0/half0; the wrap prefetch keeps the pipe primed forever.
    f16x8 buf[5];
#pragma unroll
    for (int s = 0; s < 5; ++s)
        buf[s] = *(const f16x8*)(wp0 + (size_t)s * 512);

    for (int t = 0; t < T_SZ; ++t) {
        const f16* hb = hbufA + cur * (R14 * LDA);
        f16*       hn = hbufA + (cur ^ 1) * (R14 * LDA);
        // token ids for this step (wave-local rows)
        int vr[2][4];
#pragma unroll
        for (int rt = 0; rt < 2; ++rt)
#pragma unroll
            for (int r = 0; r < 4; ++r)
                vr[rt][r] = capv[(rt * 16 + q * 4 + r) * T_SZ + t];
#pragma unroll
        for (int nt = 0; nt < 3; ++nt) {
            if (nt < tcnt) {
                int col = (tstart + nt) * 16 + c;
                // x-preact gather: issued at tile start, consumed ~80 MFMAs later
                f16x4 xi0[4], xi1[4];
#pragma unroll
                for (int r = 0; r < 4; ++r) {
                    xi0[r] = *(const f16x4*)(embX + (size_t)vr[0][r] * G4 + col * 4);
                    xi1[r] = *(const f16x4*)(embX + (size_t)vr[1][r] * G4 + col * 4);
                }
                f32x4 ac[4][2];
#pragma unroll
                for (int g = 0; g < 4; ++g) {
                    ac[g][0] = (f32x4){0.f, 0.f, 0.f, 0.f};
                    ac[g][1] = (f32x4){0.f, 0.f, 0.f, 0.f};
                }
#pragma unroll
                for (int h = 0; h < 2; ++h) {
                    // A fragments for this K-half, both row-tiles (40 regs)
                    f16x8 afr0[5], afr1[5];
#pragma unroll
                    for (int k = 0; k < 5; ++k) {
                        afr0[k] = *(const f16x8*)(hb + c * LDA + (h * 5 + k) * 32 + q * 8);
                        afr1[k] = *(const f16x8*)(hb + (16 + c) * LDA + (h * 5 + k) * 32 + q * 8);
                    }
#pragma unroll
                    for (int g = 0; g < 4; ++g) {
                        // prefetch target: next (nt,g,h) in consumption order;
                        // at the tile's end wrap to next tile / next step's start
                        int nb = (g < 3) ? (nt * 40 + (g + 1) * 10 + h * 5)
                               : (h == 0) ? (nt * 40 + 5)
                               : ((nt + 1 < tcnt) ? (nt + 1) * 40 : 0);
#pragma unroll
                        for (int k = 0; k < 5; ++k) {
                            ac[g][0] = __builtin_amdgcn_mfma_f32_16x16x32_f16(afr0[k], buf[k], ac[g][0], 0, 0, 0);
                            ac[g][1] = __builtin_amdgcn_mfma_f32_16x16x32_f16(afr1[k], buf[k], ac[g][1], 0, 0, 0);
                            buf[k] = *(const f16x8*)(wp0 + (size_t)(nb + k) * 512);
                        }
                    }
                }
                // cell update: rows rt*16 + q*4 + r, column col
#pragma unroll
                for (int rt = 0; rt < 2; ++rt)
#pragma unroll
                    for (int r = 0; r < 4; ++r) {
                        f16x4 xv = rt ? xi1[r] : xi0[r];
                        float gi = ac[0][rt][r] + (float)xv[0];
                        float gf = ac[1][rt][r] + (float)xv[1];
                        float gg = ac[2][rt][r] + (float)xv[2];
                        float go = ac[3][rt][r] + (float)xv[3];
                        float ii = sigmoid_f(gi);
                        float ff = sigmoid_f(gf);
                        float gt = tanh_f(gg);
                        float oo = sigmoid_f(go);
                        int row = rt * 16 + q * 4 + r;
                        int ci = row * LDC + col;
                        float cn = ff * cbuf[ci] + ii * gt;
                        cbuf[ci] = cn;
                        float hh = oo * tanh_f(cn);
                        hn[row * LDA + col] = (f16)hh;
                        if (t == lens[row] - 1)
                            hlast[(size_t)(b0 + row) * GP + col] = hh;
                    }
            }
        }
        __syncthreads();
        cur ^= 1;
    }
}

// kR8 (fallback, proven): fused [h|x] recurrence for small-ws runs.
__global__ __launch_bounds__(512, 2)
void kR8(const int* __restrict__ cap,
         const int* __restrict__ cap_len,
         const f16* __restrict__ embT,
         const f16* __restrict__ Wpk,
         const float* __restrict__ biasp,
         float* __restrict__ hlast) {
    extern __shared__ __align__(16) char smem[];
    f16*   hbuf  = (f16*)smem;                          // 10496
    f16*   xbuf  = (f16*)(smem + 10496);                // 10496
    f16*   gates = (f16*)(smem + 20992);                // 39168
    float* biasL = (float*)(smem + 60160);              // 4864
    int*   capv  = (int*)(smem + 65024);                // 2048
    int*   lens  = (int*)(smem + 67072);                // 64
    int tid = threadIdx.x;
    int b0 = blockIdx.x * 16;
    if (tid < 16) lens[tid] = cap_len[b0 + tid];
    for (int i = tid; i < 16 * T_SZ; i += 512) capv[i] = cap[(size_t)b0 * T_SZ + i];
    for (int i = tid; i < 16 * LDA; i += 512) hbuf[i] = (f16)0.f;
    for (int i = tid; i < G4; i += 512) biasL[i] = biasp[i];
    __syncthreads();
    for (int i = tid; i < 16 * 40; i += 512) {
        int m = i / 40, c8 = i - m * 40;
        int v = capv[m * T_SZ + 0];
        *(f16x8*)(xbuf + m * LDA + c8 * 8) = *(const f16x8*)(embT + (size_t)v * KP + c8 * 8);
    }
    __syncthreads();
    int wave = tid >> 6, lane = tid & 63;
    int c = lane & 15, q = lane >> 4;
    int gate = wave >> 1, half = wave & 1;
    int nt0 = half * 10, ntiles = half ? 9 : 10;
    const f16* wp0 = Wpk + ((size_t)((gate * 19 + nt0) * 20) * 64 + lane) * 8;
    const f16* hrow = hbuf + c * LDA + q * 8;
    const f16* xrow = xbuf + c * LDA + q * 8;
    float creg[10];
#pragma unroll
    for (int i = 0; i < 10; ++i) creg[i] = 0.f;

    for (int t = 0; t < T_SZ; ++t) {
        f16x8 afr[10];
#pragma unroll
        for (int k = 0; k < 10; ++k)
            afr[k] = *(const f16x8*)(hrow + k * 32);
        f16x8 buf[10];
#pragma unroll
        for (int s = 0; s < 10; ++s)
            buf[s] = *(const f16x8*)(wp0 + (size_t)s * 512);
#pragma unroll 1
        for (int nt = 0; nt < ntiles - 1; ++nt) {
            int base = nt * 20;
            int ncol = gate * GP + (nt0 + nt) * 16 + c;
            float bia = biasL[ncol];
            f32x4 acch = {bia, bia, bia, bia};
            f32x4 accx = {0.f, 0.f, 0.f, 0.f};
#pragma unroll
            for (int k = 0; k < 20; ++k) {
                if (k < 10) {
                    acch = __builtin_amdgcn_mfma_f32_16x16x32_f16(afr[k], buf[k % 10], acch, 0, 0, 0);
                } else {
                    f16x8 a = *(const f16x8*)(xrow + (k - 10) * 32);
                    accx = __builtin_amdgcn_mfma_f32_16x16x32_f16(a, buf[k % 10], accx, 0, 0, 0);
                }
                buf[k % 10] = *(const f16x8*)(wp0 + (size_t)(base + k + 10) * 512);
            }
#pragma unroll
            for (int r = 0; r < 4; ++r)
                gates[(q * 4 + r) * LDG + ncol] = (f16)(acch[r] + accx[r]);
        }
        {
            int nt = ntiles - 1;
            int base = nt * 20;
            int ncol = gate * GP + (nt0 + nt) * 16 + c;
            float bia = biasL[ncol];
            f32x4 acch = {bia, bia, bia, bia};
            f32x4 accx = {0.f, 0.f, 0.f, 0.f};
#pragma unroll
            for (int k = 0; k < 20; ++k) {
                if (k < 10) {
                    acch = __builtin_amdgcn_mfma_f32_16x16x32_f16(afr[k], buf[k % 10], acch, 0, 0, 0);
                    buf[k % 10] = *(const f16x8*)(wp0 + (size_t)(base + k + 10) * 512);
                } else {
                    f16x8 a = *(const f16x8*)(xrow + (k - 10) * 32);
                    accx = __builtin_amdgcn_mfma_f32_16x16x32_f16(a, buf[k % 10], accx, 0, 0, 0);
                }
            }
#pragma unroll
            for (int r = 0; r < 4; ++r)
                gates[(q * 4 + r) * LDG + ncol] = (f16)(acch[r] + accx[r]);
        }
        __syncthreads();
        int tp1 = t + 1;
        if (tp1 < T_SZ) {
            for (int i = tid; i < 16 * 40; i += 512) {
                int m = i / 40, c8 = i - m * 40;
                int v = capv[m * T_SZ + tp1];
                *(f16x8*)(xbuf + m * LDA + c8 * 8) =
                    *(const f16x8*)(embT + (size_t)v * KP + c8 * 8);
            }
        }
#pragma unroll
        for (int it = 0; it < 10; ++it) {
            int idx = tid + it * 512;
            int m = idx / 320, j = idx - m * 320;
            if (j < H_SZ) {
                const f16* gr = gates + m * LDG;
                float gi = (float)gr[j];
                float gf = (float)gr[GP + j];
                float gg = (float)gr[2 * GP + j];
                float go = (float)gr[3 * GP + j];
                float ii = sigmoid_f(gi);
                float ff = sigmoid_f(gf);
                float gt = tanh_f(gg);
                float oo = sigmoid_f(go);
                float cn = ff * creg[it] + ii * gt;
                creg[it] = cn;
                float hh = oo * tanh_f(cn);
                hbuf[m * LDA + j] = (f16)hh;
                if (t == lens[m] - 1) hlast[(size_t)(b0 + m) * GP + j] = hh;
            }
        }
        __syncthreads();
    }
}

// kC: out[row][cl] = hlast[row] . Wc[cl] + cls_b[cl]
__global__ void kC(const float* __restrict__ hlast, const float* __restrict__ Wc,
                   const float* __restrict__ cls_b, float* __restrict__ out) {
    int row = blockIdx.x, lane = threadIdx.x;
    const float* h = hlast + (size_t)row * GP;
    float s0 = 0.f, s1 = 0.f;
    for (int j = lane; j < H_SZ; j += 64) {
        float hv = h[j];
        s0 += hv * Wc[j];
        s1 += hv * Wc[GP + j];
    }
    for (int off = 32; off; off >>= 1) {
        s0 += __shfl_down(s0, off);
        s1 += __shfl_down(s1, off);
    }
    if (lane == 0) {
        out[row * 2 + 0] = s0 + cls_b[0];
        out[row * 2 + 1] = s1 + cls_b[1];
    }
}

extern "C" void kernel_launch(void* const* d_in, const int* in_sizes, int n_in,
                              void* d_out, int out_size, void* d_ws, size_t ws_size,
                              hipStream_t stream) {
    const int*   cap     = (const int*)d_in[0];
    const int*   cap_len = (const int*)d_in[1];
    const float* embed_w = (const float*)d_in[2];
    const float* W_ih    = (const float*)d_in[3];
    const float* W_hh    = (const float*)d_in[4];
    const float* b_ih    = (const float*)d_in[5];
    const float* b_hh    = (const float*)d_in[6];
    const float* cls_v   = (const float*)d_in[7];
    const float* cls_g   = (const float*)d_in[8];
    const float* cls_b   = (const float*)d_in[9];
    float* out = (float*)d_out;

    char* w = (char*)d_ws;
    size_t off = 0;
    auto alloc = [&](size_t bytes) -> void* {
        void* p = w + off;
        off += (bytes + 255) & ~(size_t)255;
        return p;
    };
    f16*   embT  = (f16*)alloc((size_t)VOCAB * KP * sizeof(f16));      // 6.4 MB
    f16*   Wpk   = (f16*)alloc((size_t)1520 * 64 * 8 * sizeof(f16));   // 1.56 MB
    f16*   WgS   = (f16*)alloc((size_t)800 * 64 * 8 * sizeof(f16));    // 819 KB
    float* biasp = (float*)alloc((size_t)G4 * sizeof(float));
    float* Wc    = (float*)alloc((size_t)2 * GP * sizeof(float));
    float* hlast = (float*)alloc((size_t)B_SZ * GP * sizeof(float));   // 5.0 MB
    f16*   embX  = (f16*)(w + off);                                    // 24.3 MB f16 [V][GP][4]
    size_t need_split = off + ((size_t)VOCAB * GP * 4 * sizeof(f16) + 255);
    bool split = (ws_size >= need_split);          // deterministic per run

    kP0<<<VOCAB, KP, 0, stream>>>(embed_w, embT);
    kPW2<<<1520, 64, 0, stream>>>(W_ih, W_hh, b_ih, b_hh, Wpk, biasp);
    kP2<<<1, 64, 0, stream>>>(cls_v, cls_g, Wc);
    if (split) {
        kPW4<<<800, 64, 0, stream>>>(W_hh, WgS);
        kX2<<<VOCAB / 16, 512, 0, stream>>>(embT, Wpk, biasp, embX);
        static const int smem_r16 = 85632;
        (void)hipFuncSetAttribute((const void*)kR16,
                                  hipFuncAttributeMaxDynamicSharedMemorySize, smem_r16);
        kR16<<<NB14, 512, smem_r16, stream>>>(cap, cap_len, embX, WgS, hlast);
    } else {
        static const int smem_r8 = 67072 + 64;
        (void)hipFuncSetAttribute((const void*)kR8,
                                  hipFuncAttributeMaxDynamicSharedMemorySize, smem_r8);
        kR8<<<B_SZ / 16, 512, smem_r8, stream>>>(cap, cap_len, embT, Wpk, biasp, hlast);
    }
    kC<<<B_SZ, 64, 0, stream>>>(hlast, Wc, cls_b, out);
}

// Round 5
// 1010.157 us; speedup vs baseline: 1.4541x; 1.2129x over previous
//
#include <hip/hip_runtime.h>
#include <hip/hip_fp16.h>

typedef _Float16 f16;
typedef _Float16 f16x4 __attribute__((ext_vector_type(4)));
typedef _Float16 f16x8 __attribute__((ext_vector_type(8)));
typedef float f32x4 __attribute__((ext_vector_type(4)));

#define B_SZ   4096
#define T_SZ   32
#define VOCAB  10000
#define E_SZ   300
#define H_SZ   300
#define KP     320          // embT row width (10x32)
#define GP     304          // per-gate padded N (19x16)
#define G4     1216         // 4*GP
#define LDA    328          // hbuf row stride f16
#define LDG    1224         // kR8 gates row stride f16
#define LDC    308          // cbuf row stride f32
#define G305   305          // kR18 gates per-gate col stride (f32)
#define GROW   1220         // kR18 gates per-row stride (f32) = 4*G305
#define R18    16           // rows per block
#define NB18   (B_SZ/R18)   // 256 blocks -> all CUs

__device__ __forceinline__ float sigmoid_f(float x) {
    return 1.f / (1.f + __expf(-x));
}
__device__ __forceinline__ float tanh_f(float x) {
    return 2.f / (1.f + __expf(-2.f * x)) - 1.f;
}

// P0: embed_w f32 [V][300] -> embT f16 [V][320] zero-padded
__global__ void kP0(const float* __restrict__ ew, f16* __restrict__ embT) {
    int v = blockIdx.x, k = threadIdx.x;           // 320 threads
    embT[(size_t)v * KP + k] = (k < E_SZ) ? (f16)ew[(size_t)v * E_SZ + k] : (f16)0.f;
}

// kPW2: fused-stream packing (for kX2 / kR8): block (gate,nt,k20), 1 KB each.
__global__ void kPW2(const float* __restrict__ wih, const float* __restrict__ whh,
                     const float* __restrict__ bih, const float* __restrict__ bhh,
                     f16* __restrict__ Wpk, float* __restrict__ biasp) {
    int bid = blockIdx.x;                          // 0..1519 = (gate*19+nt)*20+k
    int lane = threadIdx.x;                        // 64
    int k = bid % 20, ntg = bid / 20;
    int nt = ntg % 19, gate = ntg / 19;
    int c = lane & 15, q = lane >> 4;
    int j = nt * 16 + c;
    int src = gate * H_SZ + j;
    f16 vals[8];
#pragma unroll
    for (int jj = 0; jj < 8; ++jj) {
        int kk = k * 32 + q * 8 + jj;
        float v = 0.f;
        if (j < H_SZ) {
            if (kk < KP) { if (kk < H_SZ) v = whh[(size_t)src * H_SZ + kk]; }
            else { int kx = kk - KP; if (kx < E_SZ) v = wih[(size_t)src * E_SZ + kx]; }
        }
        vals[jj] = (f16)v;
    }
    *(f16x8*)(Wpk + ((size_t)bid * 64 + lane) * 8) = *(const f16x8*)vals;
    if (k == 0 && q == 0)
        biasp[gate * GP + j] = (j < H_SZ) ? (bih[src] + bhh[src]) : 0.f;
}

// kPW4: gate-major W_hh-only packing: block (nt, gate, k10), 1 KB each.
// 800 blocks (760 real + 40 zero slack).
__global__ void kPW4(const float* __restrict__ whh, f16* __restrict__ WgS) {
    int bid = blockIdx.x;                          // 0..799
    int lane = threadIdx.x;
    int c = lane & 15, q = lane >> 4;
    f16 vals[8];
    if (bid < 760) {
        int nt = bid / 40, g = (bid % 40) / 10, k = bid % 10;
        int j = nt * 16 + c;
        int src = g * H_SZ + j;
#pragma unroll
        for (int jj = 0; jj < 8; ++jj) {
            int kk = k * 32 + q * 8 + jj;
            float v = (j < H_SZ && kk < H_SZ) ? whh[(size_t)src * H_SZ + kk] : 0.f;
            vals[jj] = (f16)v;
        }
    } else {
#pragma unroll
        for (int jj = 0; jj < 8; ++jj) vals[jj] = (f16)0.f;
    }
    *(f16x8*)(WgS + ((size_t)bid * 64 + lane) * 8) = *(const f16x8*)vals;
}

// P2: weight-normed classifier W = g * v / ||v||  -> Wc f32 [2][GP]
__global__ void kP2(const float* __restrict__ cls_v, const float* __restrict__ cls_g,
                    float* __restrict__ Wc) {
    int lane = threadIdx.x;
    for (int cl = 0; cl < 2; ++cl) {
        float s = 0.f;
        for (int j = lane; j < H_SZ; j += 64) { float v = cls_v[cl * H_SZ + j]; s += v * v; }
        for (int off = 32; off; off >>= 1) s += __shfl_down(s, off);
        float nrm = sqrtf(__shfl(s, 0));
        float scale = cls_g[cl] / nrm;
        for (int j = lane; j < H_SZ; j += 64) Wc[cl * GP + j] = cls_v[cl * H_SZ + j] * scale;
    }
}

// kX2: per-vocab x-gate preacts, gate-interleaved f16:
// embX[v][j][gate] = (W_ih . emb[v] + b_ih + b_hh)[gate*300+j]   (row = 2432 B)
__global__ __launch_bounds__(512, 2)
void kX2(const f16* __restrict__ embT, const f16* __restrict__ Wpk,
         const float* __restrict__ biasp, f16* __restrict__ embX) {
    int tid = threadIdx.x;
    int v0 = blockIdx.x * 16;
    int wave = tid >> 6, lane = tid & 63;
    int c = lane & 15, q = lane >> 4;
    int gate = wave >> 1, half = wave & 1;
    int nt0 = half * 10, ntiles = half ? 9 : 10;
    const f16* wp0 = Wpk + (((size_t)(gate * 19 + nt0) * 20 + 10) * 64 + lane) * 8;
    f16x8 afr[10];
    const f16* arow = embT + (size_t)(v0 + c) * KP + q * 8;
#pragma unroll
    for (int k = 0; k < 10; ++k)
        afr[k] = *(const f16x8*)(arow + k * 32);
    f16x8 buf[10];
#pragma unroll
    for (int s = 0; s < 10; ++s)
        buf[s] = *(const f16x8*)(wp0 + (size_t)s * 512);
#pragma unroll 1
    for (int nt = 0; nt < ntiles - 1; ++nt) {
        int jcol = (nt0 + nt) * 16 + c;
        float bia = biasp[gate * GP + jcol];
        f32x4 acc = {bia, bia, bia, bia};
#pragma unroll
        for (int k = 0; k < 10; ++k) {
            acc = __builtin_amdgcn_mfma_f32_16x16x32_f16(afr[k], buf[k], acc, 0, 0, 0);
            buf[k] = *(const f16x8*)(wp0 + (size_t)(nt * 20 + k + 20) * 512);
        }
#pragma unroll
        for (int r = 0; r < 4; ++r)
            embX[((size_t)(v0 + q * 4 + r) * GP + jcol) * 4 + gate] = (f16)acc[r];
    }
    {
        int nt = ntiles - 1;
        int jcol = (nt0 + nt) * 16 + c;
        float bia = biasp[gate * GP + jcol];
        f32x4 acc = {bia, bia, bia, bia};
#pragma unroll
        for (int k = 0; k < 10; ++k)
            acc = __builtin_amdgcn_mfma_f32_16x16x32_f16(afr[k], buf[k], acc, 0, 0, 0);
#pragma unroll
        for (int r = 0; r < 4; ++r)
            embX[((size_t)(v0 + q * 4 + r) * GP + jcol) * 4 + gate] = (f16)acc[r];
    }
}

// kR18: 16 rows/block, 1024 threads (16 waves = 4 waves/SIMD -- 2x kR13's TLP for
// latency hiding; kR13 sat at 10.5 us/step vs its 5.7 us L2-BW floor). Register-
// safe by construction: the 4 gates split across two 8-wave groups (gp = wave>>3
// owns gates {2gp, 2gp+1}), so per-wave state = afr[10](40) + buf[5](20) + 2 acc(8)
// ~= 100 regs < the 128 cap __launch_bounds__(1024) enforces. Gate partials land in
// an LDS f32 gates buffer (disjoint plain writes, no atomics); a whole-block cell
// phase (kR8 pattern) reads gates + direct-gathered embX x-preacts, updates c (LDS),
// writes h. No xst stage (saves 78 KB LDS -> fits the 16-wave block). 2 barriers/step.
__global__ __launch_bounds__(1024)
void kR18(const int* __restrict__ cap,
          const int* __restrict__ cap_len,
          const f16* __restrict__ embX,
          const f16* __restrict__ WgS,
          float* __restrict__ hlast) {
    extern __shared__ __align__(16) char smem[];
    f16*   hbufA = (f16*)smem;                           // 2*16*LDA*2 = 20,992 B
    float* gates = (float*)(smem + 20992);               // 16*GROW*4 = 78,080 B
    float* cbuf  = (float*)(smem + 99072);               // 16*LDC*4  = 19,712 B
    int*   capv  = (int*)(smem + 118784);                // 2,048 B
    int*   lens  = (int*)(smem + 120832);                // 64 B     total 120,896
    int tid = threadIdx.x;
    int b0 = blockIdx.x * R18;
    if (tid < R18) lens[tid] = cap_len[b0 + tid];
    for (int i = tid; i < R18 * T_SZ; i += 1024) capv[i] = cap[(size_t)b0 * T_SZ + i];
    for (int i = tid; i < 2 * R18 * LDA; i += 1024) hbufA[i] = (f16)0.f;
    for (int i = tid; i < R18 * LDC; i += 1024) cbuf[i] = 0.f;
    __syncthreads();

    int wave = tid >> 6, lane = tid & 63;
    int c = lane & 15, q = lane >> 4;
    int w8 = wave & 7, gp = wave >> 3;                    // gp: gate pair {2gp,2gp+1}
    int tstart = (w8 < 5) ? 2 * w8 : 10 + 3 * (w8 - 5);   // 19 = 5x2 + 3x3
    int tcnt   = (w8 < 5) ? 2 : 3;
    const f16* wp0 = WgS + ((size_t)(tstart * 40 + gp * 20) * 64 + lane) * 8;
    int cur = 0;

    // rel chunk (nt, idx) = nt*40 + idx*5, idx = g2*2+h in 0..3 (g2: gate-of-pair,
    // h: K-half). buf[5] rotating prefetch; at the wave's region end wrap to rel 0
    // (its own start for step t+1) -> the pipe never drains.
    f16x8 buf[5];
#pragma unroll
    for (int s = 0; s < 5; ++s)
        buf[s] = *(const f16x8*)(wp0 + (size_t)s * 512);

    for (int t = 0; t < T_SZ; ++t) {
        const f16* hb = hbufA + cur * (R18 * LDA);
        f16*       hn = hbufA + (cur ^ 1) * (R18 * LDA);
        // phase A: gate-pair partial preacts via MFMA
        f16x8 afr[10];
#pragma unroll
        for (int k = 0; k < 10; ++k)
            afr[k] = *(const f16x8*)(hb + c * LDA + k * 32 + q * 8);
#pragma unroll
        for (int nt = 0; nt < 3; ++nt) {
            if (nt < tcnt) {
                int colbase = (tstart + nt) * 16 + c;
                f32x4 acg[2];
                acg[0] = (f32x4){0.f, 0.f, 0.f, 0.f};
                acg[1] = (f32x4){0.f, 0.f, 0.f, 0.f};
#pragma unroll
                for (int idx = 0; idx < 4; ++idx) {       // g2=idx>>1, h=idx&1
                    int nb = (idx < 3) ? (nt * 40 + (idx + 1) * 5)
                                       : ((nt + 1 < tcnt) ? (nt + 1) * 40 : 0);
#pragma unroll
                    for (int k = 0; k < 5; ++k) {
                        acg[idx >> 1] = __builtin_amdgcn_mfma_f32_16x16x32_f16(
                            afr[(idx & 1) * 5 + k], buf[k], acg[idx >> 1], 0, 0, 0);
                        buf[k] = *(const f16x8*)(wp0 + (size_t)(nb + k) * 512);
                    }
                }
                int gbase = (q * 4) * GROW + (gp * 2) * G305 + colbase;
#pragma unroll
                for (int r = 0; r < 4; ++r) {
                    gates[gbase + r * GROW]         = acg[0][r];
                    gates[gbase + r * GROW + G305]  = acg[1][r];
                }
            }
        }
        __syncthreads();                                   // B1: partials complete
        // phase B: cell update over 16 rows x 304 cols
#pragma unroll
        for (int it = 0; it < 5; ++it) {
            int i = tid + it * 1024;
            if (i < R18 * 304) {
                int row = i / 304, j = i - row * 304;
                int gb = row * GROW + j;
                float gi = gates[gb];
                float gf = gates[gb + G305];
                float gg = gates[gb + 2 * G305];
                float go = gates[gb + 3 * G305];
                int v = capv[row * T_SZ + t];
                f16x4 xi = *(const f16x4*)(embX + (size_t)v * G4 + j * 4);
                gi += (float)xi[0];
                gf += (float)xi[1];
                gg += (float)xi[2];
                go += (float)xi[3];
                float ii = sigmoid_f(gi);
                float ff = sigmoid_f(gf);
                float gt = tanh_f(gg);
                float oo = sigmoid_f(go);
                int ci = row * LDC + j;
                float cn = ff * cbuf[ci] + ii * gt;
                cbuf[ci] = cn;
                float hh = oo * tanh_f(cn);
                hn[row * LDA + j] = (f16)hh;
                if (j < H_SZ && t == lens[row] - 1)
                    hlast[(size_t)(b0 + row) * GP + j] = hh;
            }
        }
        __syncthreads();                                   // B2: hn ready, gates free
        cur ^= 1;
    }
}

// kR8 (fallback, proven): fused [h|x] recurrence for small-ws runs.
__global__ __launch_bounds__(512, 2)
void kR8(const int* __restrict__ cap,
         const int* __restrict__ cap_len,
         const f16* __restrict__ embT,
         const f16* __restrict__ Wpk,
         const float* __restrict__ biasp,
         float* __restrict__ hlast) {
    extern __shared__ __align__(16) char smem[];
    f16*   hbuf  = (f16*)smem;                          // 10496
    f16*   xbuf  = (f16*)(smem + 10496);                // 10496
    f16*   gates = (f16*)(smem + 20992);                // 39168
    float* biasL = (float*)(smem + 60160);              // 4864
    int*   capv  = (int*)(smem + 65024);                // 2048
    int*   lens  = (int*)(smem + 67072);                // 64
    int tid = threadIdx.x;
    int b0 = blockIdx.x * 16;
    if (tid < 16) lens[tid] = cap_len[b0 + tid];
    for (int i = tid; i < 16 * T_SZ; i += 512) capv[i] = cap[(size_t)b0 * T_SZ + i];
    for (int i = tid; i < 16 * LDA; i += 512) hbuf[i] = (f16)0.f;
    for (int i = tid; i < G4; i += 512) biasL[i] = biasp[i];
    __syncthreads();
    for (int i = tid; i < 16 * 40; i += 512) {
        int m = i / 40, c8 = i - m * 40;
        int v = capv[m * T_SZ + 0];
        *(f16x8*)(xbuf + m * LDA + c8 * 8) = *(const f16x8*)(embT + (size_t)v * KP + c8 * 8);
    }
    __syncthreads();
    int wave = tid >> 6, lane = tid & 63;
    int c = lane & 15, q = lane >> 4;
    int gate = wave >> 1, half = wave & 1;
    int nt0 = half * 10, ntiles = half ? 9 : 10;
    const f16* wp0 = Wpk + ((size_t)((gate * 19 + nt0) * 20) * 64 + lane) * 8;
    const f16* hrow = hbuf + c * LDA + q * 8;
    const f16* xrow = xbuf + c * LDA + q * 8;
    float creg[10];
#pragma unroll
    for (int i = 0; i < 10; ++i) creg[i] = 0.f;

    for (int t = 0; t < T_SZ; ++t) {
        f16x8 afr[10];
#pragma unroll
        for (int k = 0; k < 10; ++k)
            afr[k] = *(const f16x8*)(hrow + k * 32);
        f16x8 buf[10];
#pragma unroll
        for (int s = 0; s < 10; ++s)
            buf[s] = *(const f16x8*)(wp0 + (size_t)s * 512);
#pragma unroll 1
        for (int nt = 0; nt < ntiles - 1; ++nt) {
            int base = nt * 20;
            int ncol = gate * GP + (nt0 + nt) * 16 + c;
            float bia = biasL[ncol];
            f32x4 acch = {bia, bia, bia, bia};
            f32x4 accx = {0.f, 0.f, 0.f, 0.f};
#pragma unroll
            for (int k = 0; k < 20; ++k) {
                if (k < 10) {
                    acch = __builtin_amdgcn_mfma_f32_16x16x32_f16(afr[k], buf[k % 10], acch, 0, 0, 0);
                } else {
                    f16x8 a = *(const f16x8*)(xrow + (k - 10) * 32);
                    accx = __builtin_amdgcn_mfma_f32_16x16x32_f16(a, buf[k % 10], accx, 0, 0, 0);
                }
                buf[k % 10] = *(const f16x8*)(wp0 + (size_t)(base + k + 10) * 512);
            }
#pragma unroll
            for (int r = 0; r < 4; ++r)
                gates[(q * 4 + r) * LDG + ncol] = (f16)(acch[r] + accx[r]);
        }
        {
            int nt = ntiles - 1;
            int base = nt * 20;
            int ncol = gate * GP + (nt0 + nt) * 16 + c;
            float bia = biasL[ncol];
            f32x4 acch = {bia, bia, bia, bia};
            f32x4 accx = {0.f, 0.f, 0.f, 0.f};
#pragma unroll
            for (int k = 0; k < 20; ++k) {
                if (k < 10) {
                    acch = __builtin_amdgcn_mfma_f32_16x16x32_f16(afr[k], buf[k % 10], acch, 0, 0, 0);
                    buf[k % 10] = *(const f16x8*)(wp0 + (size_t)(base + k + 10) * 512);
                } else {
                    f16x8 a = *(const f16x8*)(xrow + (k - 10) * 32);
                    accx = __builtin_amdgcn_mfma_f32_16x16x32_f16(a, buf[k % 10], accx, 0, 0, 0);
                }
            }
#pragma unroll
            for (int r = 0; r < 4; ++r)
                gates[(q * 4 + r) * LDG + ncol] = (f16)(acch[r] + accx[r]);
        }
        __syncthreads();
        int tp1 = t + 1;
        if (tp1 < T_SZ) {
            for (int i = tid; i < 16 * 40; i += 512) {
                int m = i / 40, c8 = i - m * 40;
                int v = capv[m * T_SZ + tp1];
                *(f16x8*)(xbuf + m * LDA + c8 * 8) =
                    *(const f16x8*)(embT + (size_t)v * KP + c8 * 8);
            }
        }
#pragma unroll
        for (int it = 0; it < 10; ++it) {
            int idx = tid + it * 512;
            int m = idx / 320, j = idx - m * 320;
            if (j < H_SZ) {
                const f16* gr = gates + m * LDG;
                float gi = (float)gr[j];
                float gf = (float)gr[GP + j];
                float gg = (float)gr[2 * GP + j];
                float go = (float)gr[3 * GP + j];
                float ii = sigmoid_f(gi);
                float ff = sigmoid_f(gf);
                float gt = tanh_f(gg);
                float oo = sigmoid_f(go);
                float cn = ff * creg[it] + ii * gt;
                creg[it] = cn;
                float hh = oo * tanh_f(cn);
                hbuf[m * LDA + j] = (f16)hh;
                if (t == lens[m] - 1) hlast[(size_t)(b0 + m) * GP + j] = hh;
            }
        }
        __syncthreads();
    }
}

// kC: out[row][cl] = hlast[row] . Wc[cl] + cls_b[cl]
__global__ void kC(const float* __restrict__ hlast, const float* __restrict__ Wc,
                   const float* __restrict__ cls_b, float* __restrict__ out) {
    int row = blockIdx.x, lane = threadIdx.x;
    const float* h = hlast + (size_t)row * GP;
    float s0 = 0.f, s1 = 0.f;
    for (int j = lane; j < H_SZ; j += 64) {
        float hv = h[j];
        s0 += hv * Wc[j];
        s1 += hv * Wc[GP + j];
    }
    for (int off = 32; off; off >>= 1) {
        s0 += __shfl_down(s0, off);
        s1 += __shfl_down(s1, off);
    }
    if (lane == 0) {
        out[row * 2 + 0] = s0 + cls_b[0];
        out[row * 2 + 1] = s1 + cls_b[1];
    }
}

extern "C" void kernel_launch(void* const* d_in, const int* in_sizes, int n_in,
                              void* d_out, int out_size, void* d_ws, size_t ws_size,
                              hipStream_t stream) {
    const int*   cap     = (const int*)d_in[0];
    const int*   cap_len = (const int*)d_in[1];
    const float* embed_w = (const float*)d_in[2];
    const float* W_ih    = (const float*)d_in[3];
    const float* W_hh    = (const float*)d_in[4];
    const float* b_ih    = (const float*)d_in[5];
    const float* b_hh    = (const float*)d_in[6];
    const float* cls_v   = (const float*)d_in[7];
    const float* cls_g   = (const float*)d_in[8];
    const float* cls_b   = (const float*)d_in[9];
    float* out = (float*)d_out;

    char* w = (char*)d_ws;
    size_t off = 0;
    auto alloc = [&](size_t bytes) -> void* {
        void* p = w + off;
        off += (bytes + 255) & ~(size_t)255;
        return p;
    };
    f16*   embT  = (f16*)alloc((size_t)VOCAB * KP * sizeof(f16));      // 6.4 MB
    f16*   Wpk   = (f16*)alloc((size_t)1520 * 64 * 8 * sizeof(f16));   // 1.56 MB
    f16*   WgS   = (f16*)alloc((size_t)800 * 64 * 8 * sizeof(f16));    // 819 KB
    float* biasp = (float*)alloc((size_t)G4 * sizeof(float));
    float* Wc    = (float*)alloc((size_t)2 * GP * sizeof(float));
    float* hlast = (float*)alloc((size_t)B_SZ * GP * sizeof(float));   // 5.0 MB
    f16*   embX  = (f16*)(w + off);                                    // 24.3 MB f16 [V][GP][4]
    size_t need_split = off + ((size_t)VOCAB * GP * 4 * sizeof(f16) + 255);
    bool split = (ws_size >= need_split);          // deterministic per run

    kP0<<<VOCAB, KP, 0, stream>>>(embed_w, embT);
    kPW2<<<1520, 64, 0, stream>>>(W_ih, W_hh, b_ih, b_hh, Wpk, biasp);
    kP2<<<1, 64, 0, stream>>>(cls_v, cls_g, Wc);
    if (split) {
        kPW4<<<800, 64, 0, stream>>>(W_hh, WgS);
        kX2<<<VOCAB / 16, 512, 0, stream>>>(embT, Wpk, biasp, embX);
        static const int smem_r18 = 120896;
        (void)hipFuncSetAttribute((const void*)kR18,
                                  hipFuncAttributeMaxDynamicSharedMemorySize, smem_r18);
        kR18<<<NB18, 1024, smem_r18, stream>>>(cap, cap_len, embX, WgS, hlast);
    } else {
        static const int smem_r8 = 67072 + 64;
        (void)hipFuncSetAttribute((const void*)kR8,
                                  hipFuncAttributeMaxDynamicSharedMemorySize, smem_r8);
        kR8<<<B_SZ / 16, 512, smem_r8, stream>>>(cap, cap_len, embT, Wpk, biasp, hlast);
    }
    kC<<<B_SZ, 64, 0, stream>>>(hlast, Wc, cls_b, out);
}

// Round 6
// 961.710 us; speedup vs baseline: 1.5274x; 1.0504x over previous
//
#include <hip/hip_runtime.h>
#include <hip/hip_fp16.h>

typedef _Float16 f16;
typedef _Float16 f16x4 __attribute__((ext_vector_type(4)));
typedef _Float16 f16x8 __attribute__((ext_vector_type(8)));
typedef float f32x4 __attribute__((ext_vector_type(4)));

#define B_SZ   4096
#define T_SZ   32
#define VOCAB  10000
#define E_SZ   300
#define H_SZ   300
#define KP     320          // embT row width (10x32)
#define GP     304          // per-gate padded N (19x16)
#define G4     1216         // 4*GP
#define LDA    328          // hbuf row stride f16
#define LDG    1224         // kR8 gates row stride f16
#define LDC    308          // cbuf row stride f32
#define G305   305          // kR19 gates per-gate col stride (f32)
#define GROW   1220         // kR19 gates per-row stride (f32) = 4*G305
#define R18    16           // rows per block
#define NB18   (B_SZ/R18)   // 256 blocks -> all CUs

__device__ __forceinline__ float sigmoid_f(float x) {
    return 1.f / (1.f + __expf(-x));
}
__device__ __forceinline__ float tanh_f(float x) {
    return 2.f / (1.f + __expf(-2.f * x)) - 1.f;
}

// P0: embed_w f32 [V][300] -> embT f16 [V][320] zero-padded
__global__ void kP0(const float* __restrict__ ew, f16* __restrict__ embT) {
    int v = blockIdx.x, k = threadIdx.x;           // 320 threads
    embT[(size_t)v * KP + k] = (k < E_SZ) ? (f16)ew[(size_t)v * E_SZ + k] : (f16)0.f;
}

// kPW2: fused-stream packing (for kX2 / kR8): block (gate,nt,k20), 1 KB each.
__global__ void kPW2(const float* __restrict__ wih, const float* __restrict__ whh,
                     const float* __restrict__ bih, const float* __restrict__ bhh,
                     f16* __restrict__ Wpk, float* __restrict__ biasp) {
    int bid = blockIdx.x;                          // 0..1519 = (gate*19+nt)*20+k
    int lane = threadIdx.x;                        // 64
    int k = bid % 20, ntg = bid / 20;
    int nt = ntg % 19, gate = ntg / 19;
    int c = lane & 15, q = lane >> 4;
    int j = nt * 16 + c;
    int src = gate * H_SZ + j;
    f16 vals[8];
#pragma unroll
    for (int jj = 0; jj < 8; ++jj) {
        int kk = k * 32 + q * 8 + jj;
        float v = 0.f;
        if (j < H_SZ) {
            if (kk < KP) { if (kk < H_SZ) v = whh[(size_t)src * H_SZ + kk]; }
            else { int kx = kk - KP; if (kx < E_SZ) v = wih[(size_t)src * E_SZ + kx]; }
        }
        vals[jj] = (f16)v;
    }
    *(f16x8*)(Wpk + ((size_t)bid * 64 + lane) * 8) = *(const f16x8*)vals;
    if (k == 0 && q == 0)
        biasp[gate * GP + j] = (j < H_SZ) ? (bih[src] + bhh[src]) : 0.f;
}

// kPW4: gate-major W_hh-only packing: block (nt, gate, k10), 1 KB each.
// 800 blocks (760 real + 40 zero slack).
__global__ void kPW4(const float* __restrict__ whh, f16* __restrict__ WgS) {
    int bid = blockIdx.x;                          // 0..799
    int lane = threadIdx.x;
    int c = lane & 15, q = lane >> 4;
    f16 vals[8];
    if (bid < 760) {
        int nt = bid / 40, g = (bid % 40) / 10, k = bid % 10;
        int j = nt * 16 + c;
        int src = g * H_SZ + j;
#pragma unroll
        for (int jj = 0; jj < 8; ++jj) {
            int kk = k * 32 + q * 8 + jj;
            float v = (j < H_SZ && kk < H_SZ) ? whh[(size_t)src * H_SZ + kk] : 0.f;
            vals[jj] = (f16)v;
        }
    } else {
#pragma unroll
        for (int jj = 0; jj < 8; ++jj) vals[jj] = (f16)0.f;
    }
    *(f16x8*)(WgS + ((size_t)bid * 64 + lane) * 8) = *(const f16x8*)vals;
}

// P2: weight-normed classifier W = g * v / ||v||  -> Wc f32 [2][GP]
__global__ void kP2(const float* __restrict__ cls_v, const float* __restrict__ cls_g,
                    float* __restrict__ Wc) {
    int lane = threadIdx.x;
    for (int cl = 0; cl < 2; ++cl) {
        float s = 0.f;
        for (int j = lane; j < H_SZ; j += 64) { float v = cls_v[cl * H_SZ + j]; s += v * v; }
        for (int off = 32; off; off >>= 1) s += __shfl_down(s, off);
        float nrm = sqrtf(__shfl(s, 0));
        float scale = cls_g[cl] / nrm;
        for (int j = lane; j < H_SZ; j += 64) Wc[cl * GP + j] = cls_v[cl * H_SZ + j] * scale;
    }
}

// kX2: per-vocab x-gate preacts, gate-interleaved f16:
// embX[v][j][gate] = (W_ih . emb[v] + b_ih + b_hh)[gate*300+j]   (row = 2432 B)
__global__ __launch_bounds__(512, 2)
void kX2(const f16* __restrict__ embT, const f16* __restrict__ Wpk,
         const float* __restrict__ biasp, f16* __restrict__ embX) {
    int tid = threadIdx.x;
    int v0 = blockIdx.x * 16;
    int wave = tid >> 6, lane = tid & 63;
    int c = lane & 15, q = lane >> 4;
    int gate = wave >> 1, half = wave & 1;
    int nt0 = half * 10, ntiles = half ? 9 : 10;
    const f16* wp0 = Wpk + (((size_t)(gate * 19 + nt0) * 20 + 10) * 64 + lane) * 8;
    f16x8 afr[10];
    const f16* arow = embT + (size_t)(v0 + c) * KP + q * 8;
#pragma unroll
    for (int k = 0; k < 10; ++k)
        afr[k] = *(const f16x8*)(arow + k * 32);
    f16x8 buf[10];
#pragma unroll
    for (int s = 0; s < 10; ++s)
        buf[s] = *(const f16x8*)(wp0 + (size_t)s * 512);
#pragma unroll 1
    for (int nt = 0; nt < ntiles - 1; ++nt) {
        int jcol = (nt0 + nt) * 16 + c;
        float bia = biasp[gate * GP + jcol];
        f32x4 acc = {bia, bia, bia, bia};
#pragma unroll
        for (int k = 0; k < 10; ++k) {
            acc = __builtin_amdgcn_mfma_f32_16x16x32_f16(afr[k], buf[k], acc, 0, 0, 0);
            buf[k] = *(const f16x8*)(wp0 + (size_t)(nt * 20 + k + 20) * 512);
        }
#pragma unroll
        for (int r = 0; r < 4; ++r)
            embX[((size_t)(v0 + q * 4 + r) * GP + jcol) * 4 + gate] = (f16)acc[r];
    }
    {
        int nt = ntiles - 1;
        int jcol = (nt0 + nt) * 16 + c;
        float bia = biasp[gate * GP + jcol];
        f32x4 acc = {bia, bia, bia, bia};
#pragma unroll
        for (int k = 0; k < 10; ++k)
            acc = __builtin_amdgcn_mfma_f32_16x16x32_f16(afr[k], buf[k], acc, 0, 0, 0);
#pragma unroll
        for (int r = 0; r < 4; ++r)
            embX[((size_t)(v0 + q * 4 + r) * GP + jcol) * 4 + gate] = (f16)acc[r];
    }
}

// kR19: kR18 (passing) with register demand cut to ~60 so it fits even the
// allocator's worst-case 64-reg budget (observed: 512-thr MFMA kernels get 128,
// 1024-thr get 64 -- the backend targets 2 blocks/CU since it can't see dynamic
// LDS; launch_bounds/waves_per_eu only CAP the budget, never raise it; kR14/15/16/18
// all spilled into GBs of scratch). Changes vs kR18: afr[10] -> afr[5] with h-major
// inner order (idx = h*2+g2; each K-half loaded once, shared by both gates of the
// pair), acg as two named f32x4, waves_per_eu(4,4) insurance. Everything else
// (gp-split phase A, f32 gates LDS, cbuf, 2 barriers/step) identical to kR18.
__global__ __launch_bounds__(1024)
__attribute__((amdgpu_waves_per_eu(4, 4)))
void kR19(const int* __restrict__ cap,
          const int* __restrict__ cap_len,
          const f16* __restrict__ embX,
          const f16* __restrict__ WgS,
          float* __restrict__ hlast) {
    extern __shared__ __align__(16) char smem[];
    f16*   hbufA = (f16*)smem;                           // 2*16*LDA*2 = 20,992 B
    float* gates = (float*)(smem + 20992);               // 16*GROW*4 = 78,080 B
    float* cbuf  = (float*)(smem + 99072);               // 16*LDC*4  = 19,712 B
    int*   capv  = (int*)(smem + 118784);                // 2,048 B
    int*   lens  = (int*)(smem + 120832);                // 64 B     total 120,896
    int tid = threadIdx.x;
    int b0 = blockIdx.x * R18;
    if (tid < R18) lens[tid] = cap_len[b0 + tid];
    for (int i = tid; i < R18 * T_SZ; i += 1024) capv[i] = cap[(size_t)b0 * T_SZ + i];
    for (int i = tid; i < 2 * R18 * LDA; i += 1024) hbufA[i] = (f16)0.f;
    for (int i = tid; i < R18 * LDC; i += 1024) cbuf[i] = 0.f;
    __syncthreads();

    int wave = tid >> 6, lane = tid & 63;
    int c = lane & 15, q = lane >> 4;
    int w8 = wave & 7, gp = wave >> 3;                    // gp: gate pair {2gp,2gp+1}
    int tstart = (w8 < 5) ? 2 * w8 : 10 + 3 * (w8 - 5);   // 19 = 5x2 + 3x3
    int tcnt   = (w8 < 5) ? 2 : 3;
    const f16* wp0 = WgS + ((size_t)(tstart * 40 + gp * 20) * 64 + lane) * 8;
    int cur = 0;

    // rel chunk (nt, g2, h) = nt*40 + g2*10 + h*5 relative to wp0.
    // consumption order h-major: idx = h*2+g2 -> rel seq 0,10,5,15 per tile.
    // buf[5] rotating prefetch; wrap at region end to rel 0 (next step's start).
    f16x8 buf[5];
#pragma unroll
    for (int s = 0; s < 5; ++s)
        buf[s] = *(const f16x8*)(wp0 + (size_t)s * 512);

    for (int t = 0; t < T_SZ; ++t) {
        const f16* hb = hbufA + cur * (R18 * LDA);
        f16*       hn = hbufA + (cur ^ 1) * (R18 * LDA);
        // phase A: gate-pair partial preacts via MFMA
#pragma unroll
        for (int nt = 0; nt < 3; ++nt) {
            if (nt < tcnt) {
                int col = (tstart + nt) * 16 + c;
                f32x4 acg0 = {0.f, 0.f, 0.f, 0.f};
                f32x4 acg1 = {0.f, 0.f, 0.f, 0.f};
                f16x8 afr[5];
#pragma unroll
                for (int idx = 0; idx < 4; ++idx) {       // h = idx>>1, g2 = idx&1
                    int h = idx >> 1;
                    if ((idx & 1) == 0) {                 // (re)load A-half, shared by both gates
#pragma unroll
                        for (int k = 0; k < 5; ++k)
                            afr[k] = *(const f16x8*)(hb + c * LDA + (h * 5 + k) * 32 + q * 8);
                    }
                    int nb = (idx == 0) ? nt * 40 + 10
                           : (idx == 1) ? nt * 40 + 5
                           : (idx == 2) ? nt * 40 + 15
                                        : ((nt + 1 < tcnt) ? (nt + 1) * 40 : 0);
#pragma unroll
                    for (int k = 0; k < 5; ++k) {
                        if ((idx & 1) == 0)
                            acg0 = __builtin_amdgcn_mfma_f32_16x16x32_f16(afr[k], buf[k], acg0, 0, 0, 0);
                        else
                            acg1 = __builtin_amdgcn_mfma_f32_16x16x32_f16(afr[k], buf[k], acg1, 0, 0, 0);
                        buf[k] = *(const f16x8*)(wp0 + (size_t)(nb + k) * 512);
                    }
                }
                int gbase = (q * 4) * GROW + (gp * 2) * G305 + col;
#pragma unroll
                for (int r = 0; r < 4; ++r) {
                    gates[gbase + r * GROW]        = acg0[r];
                    gates[gbase + r * GROW + G305] = acg1[r];
                }
            }
        }
        __syncthreads();                                   // B1: partials complete
        // phase B: cell update over 16 rows x 320 cols (j<300 real)
#pragma unroll
        for (int it = 0; it < 5; ++it) {
            int i = tid + it * 1024;                       // 16*320 = 5120 exact
            int m = i / 320, j = i - m * 320;
            if (j < H_SZ) {
                int gb = m * GROW + j;
                float gi = gates[gb];
                float gf = gates[gb + G305];
                float gg = gates[gb + 2 * G305];
                float go = gates[gb + 3 * G305];
                int v = capv[m * T_SZ + t];
                f16x4 xi = *(const f16x4*)(embX + (size_t)v * G4 + j * 4);
                gi += (float)xi[0];
                gf += (float)xi[1];
                gg += (float)xi[2];
                go += (float)xi[3];
                float ii = sigmoid_f(gi);
                float ff = sigmoid_f(gf);
                float gt = tanh_f(gg);
                float oo = sigmoid_f(go);
                int ci = m * LDC + j;
                float cn = ff * cbuf[ci] + ii * gt;
                cbuf[ci] = cn;
                float hh = oo * tanh_f(cn);
                hn[m * LDA + j] = (f16)hh;
                if (t == lens[m] - 1)
                    hlast[(size_t)(b0 + m) * GP + j] = hh;
            }
        }
        __syncthreads();                                   // B2: hn ready, gates free
        cur ^= 1;
    }
}

// kR8 (fallback, proven): fused [h|x] recurrence for small-ws runs.
__global__ __launch_bounds__(512, 2)
void kR8(const int* __restrict__ cap,
         const int* __restrict__ cap_len,
         const f16* __restrict__ embT,
         const f16* __restrict__ Wpk,
         const float* __restrict__ biasp,
         float* __restrict__ hlast) {
    extern __shared__ __align__(16) char smem[];
    f16*   hbuf  = (f16*)smem;                          // 10496
    f16*   xbuf  = (f16*)(smem + 10496);                // 10496
    f16*   gates = (f16*)(smem + 20992);                // 39168
    float* biasL = (float*)(smem + 60160);              // 4864
    int*   capv  = (int*)(smem + 65024);                // 2048
    int*   lens  = (int*)(smem + 67072);                // 64
    int tid = threadIdx.x;
    int b0 = blockIdx.x * 16;
    if (tid < 16) lens[tid] = cap_len[b0 + tid];
    for (int i = tid; i < 16 * T_SZ; i += 512) capv[i] = cap[(size_t)b0 * T_SZ + i];
    for (int i = tid; i < 16 * LDA; i += 512) hbuf[i] = (f16)0.f;
    for (int i = tid; i < G4; i += 512) biasL[i] = biasp[i];
    __syncthreads();
    for (int i = tid; i < 16 * 40; i += 512) {
        int m = i / 40, c8 = i - m * 40;
        int v = capv[m * T_SZ + 0];
        *(f16x8*)(xbuf + m * LDA + c8 * 8) = *(const f16x8*)(embT + (size_t)v * KP + c8 * 8);
    }
    __syncthreads();
    int wave = tid >> 6, lane = tid & 63;
    int c = lane & 15, q = lane >> 4;
    int gate = wave >> 1, half = wave & 1;
    int nt0 = half * 10, ntiles = half ? 9 : 10;
    const f16* wp0 = Wpk + ((size_t)((gate * 19 + nt0) * 20) * 64 + lane) * 8;
    const f16* hrow = hbuf + c * LDA + q * 8;
    const f16* xrow = xbuf + c * LDA + q * 8;
    float creg[10];
#pragma unroll
    for (int i = 0; i < 10; ++i) creg[i] = 0.f;

    for (int t = 0; t < T_SZ; ++t) {
        f16x8 afr[10];
#pragma unroll
        for (int k = 0; k < 10; ++k)
            afr[k] = *(const f16x8*)(hrow + k * 32);
        f16x8 buf[10];
#pragma unroll
        for (int s = 0; s < 10; ++s)
            buf[s] = *(const f16x8*)(wp0 + (size_t)s * 512);
#pragma unroll 1
        for (int nt = 0; nt < ntiles - 1; ++nt) {
            int base = nt * 20;
            int ncol = gate * GP + (nt0 + nt) * 16 + c;
            float bia = biasL[ncol];
            f32x4 acch = {bia, bia, bia, bia};
            f32x4 accx = {0.f, 0.f, 0.f, 0.f};
#pragma unroll
            for (int k = 0; k < 20; ++k) {
                if (k < 10) {
                    acch = __builtin_amdgcn_mfma_f32_16x16x32_f16(afr[k], buf[k % 10], acch, 0, 0, 0);
                } else {
                    f16x8 a = *(const f16x8*)(xrow + (k - 10) * 32);
                    accx = __builtin_amdgcn_mfma_f32_16x16x32_f16(a, buf[k % 10], accx, 0, 0, 0);
                }
                buf[k % 10] = *(const f16x8*)(wp0 + (size_t)(base + k + 10) * 512);
            }
#pragma unroll
            for (int r = 0; r < 4; ++r)
                gates[(q * 4 + r) * LDG + ncol] = (f16)(acch[r] + accx[r]);
        }
        {
            int nt = ntiles - 1;
            int base = nt * 20;
            int ncol = gate * GP + (nt0 + nt) * 16 + c;
            float bia = biasL[ncol];
            f32x4 acch = {bia, bia, bia, bia};
            f32x4 accx = {0.f, 0.f, 0.f, 0.f};
#pragma unroll
            for (int k = 0; k < 20; ++k) {
                if (k < 10) {
                    acch = __builtin_amdgcn_mfma_f32_16x16x32_f16(afr[k], buf[k % 10], acch, 0, 0, 0);
                    buf[k % 10] = *(const f16x8*)(wp0 + (size_t)(base + k + 10) * 512);
                } else {
                    f16x8 a = *(const f16x8*)(xrow + (k - 10) * 32);
                    accx = __builtin_amdgcn_mfma_f32_16x16x32_f16(a, buf[k % 10], accx, 0, 0, 0);
                }
            }
#pragma unroll
            for (int r = 0; r < 4; ++r)
                gates[(q * 4 + r) * LDG + ncol] = (f16)(acch[r] + accx[r]);
        }
        __syncthreads();
        int tp1 = t + 1;
        if (tp1 < T_SZ) {
            for (int i = tid; i < 16 * 40; i += 512) {
                int m = i / 40, c8 = i - m * 40;
                int v = capv[m * T_SZ + tp1];
                *(f16x8*)(xbuf + m * LDA + c8 * 8) =
                    *(const f16x8*)(embT + (size_t)v * KP + c8 * 8);
            }
        }
#pragma unroll
        for (int it = 0; it < 10; ++it) {
            int idx = tid + it * 512;
            int m = idx / 320, j = idx - m * 320;
            if (j < H_SZ) {
                const f16* gr = gates + m * LDG;
                float gi = (float)gr[j];
                float gf = (float)gr[GP + j];
                float gg = (float)gr[2 * GP + j];
                float go = (float)gr[3 * GP + j];
                float ii = sigmoid_f(gi);
                float ff = sigmoid_f(gf);
                float gt = tanh_f(gg);
                float oo = sigmoid_f(go);
                float cn = ff * creg[it] + ii * gt;
                creg[it] = cn;
                float hh = oo * tanh_f(cn);
                hbuf[m * LDA + j] = (f16)hh;
                if (t == lens[m] - 1) hlast[(size_t)(b0 + m) * GP + j] = hh;
            }
        }
        __syncthreads();
    }
}

// kC: out[row][cl] = hlast[row] . Wc[cl] + cls_b[cl]
__global__ void kC(const float* __restrict__ hlast, const float* __restrict__ Wc,
                   const float* __restrict__ cls_b, float* __restrict__ out) {
    int row = blockIdx.x, lane = threadIdx.x;
    const float* h = hlast + (size_t)row * GP;
    float s0 = 0.f, s1 = 0.f;
    for (int j = lane; j < H_SZ; j += 64) {
        float hv = h[j];
        s0 += hv * Wc[j];
        s1 += hv * Wc[GP + j];
    }
    for (int off = 32; off; off >>= 1) {
        s0 += __shfl_down(s0, off);
        s1 += __shfl_down(s1, off);
    }
    if (lane == 0) {
        out[row * 2 + 0] = s0 + cls_b[0];
        out[row * 2 + 1] = s1 + cls_b[1];
    }
}

extern "C" void kernel_launch(void* const* d_in, const int* in_sizes, int n_in,
                              void* d_out, int out_size, void* d_ws, size_t ws_size,
                              hipStream_t stream) {
    const int*   cap     = (const int*)d_in[0];
    const int*   cap_len = (const int*)d_in[1];
    const float* embed_w = (const float*)d_in[2];
    const float* W_ih    = (const float*)d_in[3];
    const float* W_hh    = (const float*)d_in[4];
    const float* b_ih    = (const float*)d_in[5];
    const float* b_hh    = (const float*)d_in[6];
    const float* cls_v   = (const float*)d_in[7];
    const float* cls_g   = (const float*)d_in[8];
    const float* cls_b   = (const float*)d_in[9];
    float* out = (float*)d_out;

    char* w = (char*)d_ws;
    size_t off = 0;
    auto alloc = [&](size_t bytes) -> void* {
        void* p = w + off;
        off += (bytes + 255) & ~(size_t)255;
        return p;
    };
    f16*   embT  = (f16*)alloc((size_t)VOCAB * KP * sizeof(f16));      // 6.4 MB
    f16*   Wpk   = (f16*)alloc((size_t)1520 * 64 * 8 * sizeof(f16));   // 1.56 MB
    f16*   WgS   = (f16*)alloc((size_t)800 * 64 * 8 * sizeof(f16));    // 819 KB
    float* biasp = (float*)alloc((size_t)G4 * sizeof(float));
    float* Wc    = (float*)alloc((size_t)2 * GP * sizeof(float));
    float* hlast = (float*)alloc((size_t)B_SZ * GP * sizeof(float));   // 5.0 MB
    f16*   embX  = (f16*)(w + off);                                    // 24.3 MB f16 [V][GP][4]
    size_t need_split = off + ((size_t)VOCAB * GP * 4 * sizeof(f16) + 255);
    bool split = (ws_size >= need_split);          // deterministic per run

    kP0<<<VOCAB, KP, 0, stream>>>(embed_w, embT);
    kPW2<<<1520, 64, 0, stream>>>(W_ih, W_hh, b_ih, b_hh, Wpk, biasp);
    kP2<<<1, 64, 0, stream>>>(cls_v, cls_g, Wc);
    if (split) {
        kPW4<<<800, 64, 0, stream>>>(W_hh, WgS);
        kX2<<<VOCAB / 16, 512, 0, stream>>>(embT, Wpk, biasp, embX);
        static const int smem_r19 = 120896;
        (void)hipFuncSetAttribute((const void*)kR19,
                                  hipFuncAttributeMaxDynamicSharedMemorySize, smem_r19);
        kR19<<<NB18, 1024, smem_r19, stream>>>(cap, cap_len, embX, WgS, hlast);
    } else {
        static const int smem_r8 = 67072 + 64;
        (void)hipFuncSetAttribute((const void*)kR8,
                                  hipFuncAttributeMaxDynamicSharedMemorySize, smem_r8);
        kR8<<<B_SZ / 16, 512, smem_r8, stream>>>(cap, cap_len, embT, Wpk, biasp, hlast);
    }
    kC<<<B_SZ, 64, 0, stream>>>(hlast, Wc, cls_b, out);
}

// Round 7
// 409.430 us; speedup vs baseline: 3.5876x; 2.3489x over previous
//
#include <hip/hip_runtime.h>
#include <hip/hip_fp16.h>

typedef _Float16 f16;
typedef _Float16 f16x4 __attribute__((ext_vector_type(4)));
typedef _Float16 f16x8 __attribute__((ext_vector_type(8)));
typedef float f32x4 __attribute__((ext_vector_type(4)));

#define B_SZ   4096
#define T_SZ   32
#define VOCAB  10000
#define E_SZ   300
#define H_SZ   300
#define KP     320          // embT row width (10x32)
#define GP     304          // per-gate padded N (19x16)
#define G4     1216         // 4*GP
#define LDA    328          // hbuf row stride f16
#define LDG    1224         // kR8 gates row stride f16
#define LDC    308          // cbuf row stride f32
#define ROWS   16
#define NBLK   (B_SZ/ROWS)  // 256 blocks -> 1 per CU

__device__ __forceinline__ float sigmoid_f(float x) {
    return 1.f / (1.f + __expf(-x));
}
__device__ __forceinline__ float tanh_f(float x) {
    return 2.f / (1.f + __expf(-2.f * x)) - 1.f;
}

// P0: embed_w f32 [V][300] -> embT f16 [V][320] zero-padded
__global__ void kP0(const float* __restrict__ ew, f16* __restrict__ embT) {
    int v = blockIdx.x, k = threadIdx.x;           // 320 threads
    embT[(size_t)v * KP + k] = (k < E_SZ) ? (f16)ew[(size_t)v * E_SZ + k] : (f16)0.f;
}

// kPW2: fused-stream packing (for kX2 / kR8): block (gate,nt,k20), 1 KB each.
__global__ void kPW2(const float* __restrict__ wih, const float* __restrict__ whh,
                     const float* __restrict__ bih, const float* __restrict__ bhh,
                     f16* __restrict__ Wpk, float* __restrict__ biasp) {
    int bid = blockIdx.x;                          // 0..1519 = (gate*19+nt)*20+k
    int lane = threadIdx.x;                        // 64
    int k = bid % 20, ntg = bid / 20;
    int nt = ntg % 19, gate = ntg / 19;
    int c = lane & 15, q = lane >> 4;
    int j = nt * 16 + c;
    int src = gate * H_SZ + j;
    f16 vals[8];
#pragma unroll
    for (int jj = 0; jj < 8; ++jj) {
        int kk = k * 32 + q * 8 + jj;
        float v = 0.f;
        if (j < H_SZ) {
            if (kk < KP) { if (kk < H_SZ) v = whh[(size_t)src * H_SZ + kk]; }
            else { int kx = kk - KP; if (kx < E_SZ) v = wih[(size_t)src * E_SZ + kx]; }
        }
        vals[jj] = (f16)v;
    }
    *(f16x8*)(Wpk + ((size_t)bid * 64 + lane) * 8) = *(const f16x8*)vals;
    if (k == 0 && q == 0)
        biasp[gate * GP + j] = (j < H_SZ) ? (bih[src] + bhh[src]) : 0.f;
}

// kPW4: gate-major W_hh-only packing: block (nt, gate, k10), 1 KB each.
// 800 blocks (760 real + 40 zero slack).
__global__ void kPW4(const float* __restrict__ whh, f16* __restrict__ WgS) {
    int bid = blockIdx.x;                          // 0..799
    int lane = threadIdx.x;
    int c = lane & 15, q = lane >> 4;
    f16 vals[8];
    if (bid < 760) {
        int nt = bid / 40, g = (bid % 40) / 10, k = bid % 10;
        int j = nt * 16 + c;
        int src = g * H_SZ + j;
#pragma unroll
        for (int jj = 0; jj < 8; ++jj) {
            int kk = k * 32 + q * 8 + jj;
            float v = (j < H_SZ && kk < H_SZ) ? whh[(size_t)src * H_SZ + kk] : 0.f;
            vals[jj] = (f16)v;
        }
    } else {
#pragma unroll
        for (int jj = 0; jj < 8; ++jj) vals[jj] = (f16)0.f;
    }
    *(f16x8*)(WgS + ((size_t)bid * 64 + lane) * 8) = *(const f16x8*)vals;
}

// P2: weight-normed classifier W = g * v / ||v||  -> Wc f32 [2][GP]
// cols 300..303 zeroed (kR22's fused classifier multiplies h(=0) by Wc there).
__global__ void kP2(const float* __restrict__ cls_v, const float* __restrict__ cls_g,
                    float* __restrict__ Wc) {
    int lane = threadIdx.x;
    for (int cl = 0; cl < 2; ++cl) {
        float s = 0.f;
        for (int j = lane; j < H_SZ; j += 64) { float v = cls_v[cl * H_SZ + j]; s += v * v; }
        for (int off = 32; off; off >>= 1) s += __shfl_down(s, off);
        float nrm = sqrtf(__shfl(s, 0));
        float scale = cls_g[cl] / nrm;
        for (int j = lane; j < GP; j += 64)
            Wc[cl * GP + j] = (j < H_SZ) ? cls_v[cl * H_SZ + j] * scale : 0.f;
    }
}

// kX2: per-vocab x-gate preacts, gate-interleaved f16:
// embX[v][j][gate] = (W_ih . emb[v] + b_ih + b_hh)[gate*300+j]   (row = 2432 B)
__global__ __launch_bounds__(512, 2)
void kX2(const f16* __restrict__ embT, const f16* __restrict__ Wpk,
         const float* __restrict__ biasp, f16* __restrict__ embX) {
    int tid = threadIdx.x;
    int v0 = blockIdx.x * 16;
    int wave = tid >> 6, lane = tid & 63;
    int c = lane & 15, q = lane >> 4;
    int gate = wave >> 1, half = wave & 1;
    int nt0 = half * 10, ntiles = half ? 9 : 10;
    const f16* wp0 = Wpk + (((size_t)(gate * 19 + nt0) * 20 + 10) * 64 + lane) * 8;
    f16x8 afr[10];
    const f16* arow = embT + (size_t)(v0 + c) * KP + q * 8;
#pragma unroll
    for (int k = 0; k < 10; ++k)
        afr[k] = *(const f16x8*)(arow + k * 32);
    f16x8 buf[10];
#pragma unroll
    for (int s = 0; s < 10; ++s)
        buf[s] = *(const f16x8*)(wp0 + (size_t)s * 512);
#pragma unroll 1
    for (int nt = 0; nt < ntiles - 1; ++nt) {
        int jcol = (nt0 + nt) * 16 + c;
        float bia = biasp[gate * GP + jcol];
        f32x4 acc = {bia, bia, bia, bia};
#pragma unroll
        for (int k = 0; k < 10; ++k) {
            acc = __builtin_amdgcn_mfma_f32_16x16x32_f16(afr[k], buf[k], acc, 0, 0, 0);
            buf[k] = *(const f16x8*)(wp0 + (size_t)(nt * 20 + k + 20) * 512);
        }
#pragma unroll
        for (int r = 0; r < 4; ++r)
            embX[((size_t)(v0 + q * 4 + r) * GP + jcol) * 4 + gate] = (f16)acc[r];
    }
    {
        int nt = ntiles - 1;
        int jcol = (nt0 + nt) * 16 + c;
        float bia = biasp[gate * GP + jcol];
        f32x4 acc = {bia, bia, bia, bia};
#pragma unroll
        for (int k = 0; k < 10; ++k)
            acc = __builtin_amdgcn_mfma_f32_16x16x32_f16(afr[k], buf[k], acc, 0, 0, 0);
#pragma unroll
        for (int r = 0; r < 4; ++r)
            embX[((size_t)(v0 + q * 4 + r) * GP + jcol) * 4 + gate] = (f16)acc[r];
    }
}

// kR22: kR13's proven geometry (512 thr, 16 rows, 256 blocks, demand ~116 <= the
// 128-reg budget) with three stall cuts:
//  (1) xst LDS stage deleted -> x-preacts read directly from embX at tile start
//      (kR14-proven), consumed ~1.5k cyc later -> latency hidden; staging VALU gone.
//  (2) 110/760 weight chunks (14.5%, 112.6 KB) LDS-resident across all 32 steps:
//      each wave's first 1-2 (tile,gate) units, copied once at t=0 via plain
//      loads + barrier; read via ds_read_b128 (no global stall). The remaining
//      stream keeps the buf[10] rotation with kR14-style wrap prefetch (no
//      per-step preload phase).
//  (3) classifier fused: at t==tstop, shfl-reduce h*Wc over the 16-lane col
//      group, one atomicAdd per (row,cls) per wave-tile. kC + hlast deleted.
__global__ __launch_bounds__(512, 2)
void kR22(const int* __restrict__ cap,
          const int* __restrict__ cap_len,
          const f16* __restrict__ embX,
          const f16* __restrict__ WgS,
          const float* __restrict__ Wc,
          const float* __restrict__ cls_b,
          float* __restrict__ out) {
    extern __shared__ __align__(16) char smem[];
    f16*   hbufA = (f16*)smem;                           // 2*16*LDA*2 = 20,992 B
    float* cbuf  = (float*)(smem + 20992);               // 16*LDC*4  = 19,712 B
    int*   capv  = (int*)(smem + 40704);                 // 2,048 B
    int*   lens  = (int*)(smem + 42752);                 // 64 B
    f16*   wres  = (f16*)(smem + 43008);                 // 112,640 B  (total 155,648)
    int tid = threadIdx.x;
    int b0 = blockIdx.x * ROWS;
    if (tid < ROWS) lens[tid] = cap_len[b0 + tid];
    for (int i = tid; i < ROWS * T_SZ; i += 512) capv[i] = cap[(size_t)b0 * T_SZ + i];
    for (int i = tid; i < 2 * ROWS * LDA; i += 512) hbufA[i] = (f16)0.f;
    for (int i = tid; i < ROWS * LDC; i += 512) cbuf[i] = 0.f;

    int wave = tid >> 6, lane = tid & 63;
    int c = lane & 15, q = lane >> 4;
    int tstart = (wave < 5) ? 2 * wave : 10 + 3 * (wave - 5);   // 19 = 5x2 + 3x3
    int tcnt   = (wave < 5) ? 2 : 3;
    int Rw     = (wave < 5) ? 1 : 2;                             // resident units
    f16* resw = wres + ((wave < 5) ? wave * 5120 : 25600 + (wave - 5) * 10240);
    // resident fill (once; plain loads, barrier-synchronized -> no async hazards)
    for (int u = 0; u < Rw; ++u)
#pragma unroll
        for (int k = 0; k < 10; ++k)
            *(f16x8*)(resw + (u * 10 + k) * 512 + lane * 8) =
                *(const f16x8*)(WgS + ((size_t)(tstart * 40 + u * 10 + k) * 64 + lane) * 8);
    __syncthreads();

    const f16* wp0 = WgS + ((size_t)(tstart * 40) * 64 + lane) * 8;
    int cur = 0;
    // prologue: buf holds the first STREAMED unit (tile tstart, gate Rw);
    // the wrap prefetch at each step's last streamed unit keeps it primed forever.
    f16x8 buf[10];
#pragma unroll
    for (int s = 0; s < 10; ++s)
        buf[s] = *(const f16x8*)(wp0 + (size_t)(Rw * 10 + s) * 512);

    for (int t = 0; t < T_SZ; ++t) {
        const f16* hb = hbufA + cur * (ROWS * LDA);
        f16*       hn = hbufA + (cur ^ 1) * (ROWS * LDA);
        f16x8 afr[10];
#pragma unroll
        for (int k = 0; k < 10; ++k)
            afr[k] = *(const f16x8*)(hb + c * LDA + k * 32 + q * 8);
#pragma unroll 1
        for (int nt = 0; nt < tcnt; ++nt) {
            int col = (tstart + nt) * 16 + c;
            // x-preacts: direct gather, issued here, consumed after 40 MFMAs
            f16x4 xi[4];
#pragma unroll
            for (int r = 0; r < 4; ++r) {
                int v = capv[(q * 4 + r) * T_SZ + t];
                xi[r] = *(const f16x4*)(embX + (size_t)v * G4 + col * 4);
            }
            f32x4 acc0 = {0.f, 0.f, 0.f, 0.f};
            f32x4 acc1 = {0.f, 0.f, 0.f, 0.f};
            f32x4 acc2 = {0.f, 0.f, 0.f, 0.f};
            f32x4 acc3 = {0.f, 0.f, 0.f, 0.f};
#pragma unroll
            for (int g = 0; g < 4; ++g) {
                f32x4* ag = (g == 0) ? &acc0 : (g == 1) ? &acc1 : (g == 2) ? &acc2 : &acc3;
                if (nt == 0 && g < Rw) {
                    // resident unit: frags from LDS, no global issue
                    const f16* rb = resw + g * 5120 + lane * 8;
#pragma unroll
                    for (int k = 0; k < 10; ++k)
                        *ag = __builtin_amdgcn_mfma_f32_16x16x32_f16(
                            afr[k], *(const f16x8*)(rb + k * 512), *ag, 0, 0, 0);
                } else {
                    // streamed unit: consume buf, prefetch next streamed unit
                    int nbase = (g < 3) ? (nt * 40 + (g + 1) * 10)
                              : ((nt + 1 < tcnt) ? (nt + 1) * 40 : Rw * 10);
#pragma unroll
                    for (int k = 0; k < 10; ++k) {
                        *ag = __builtin_amdgcn_mfma_f32_16x16x32_f16(
                            afr[k], buf[k], *ag, 0, 0, 0);
                        buf[k] = *(const f16x8*)(wp0 + (size_t)(nbase + k) * 512);
                    }
                }
            }
            // cell update + fused classifier
#pragma unroll
            for (int r = 0; r < 4; ++r) {
                int row = q * 4 + r;
                f16x4 xv = xi[r];
                float gi = acc0[r] + (float)xv[0];
                float gf = acc1[r] + (float)xv[1];
                float gg = acc2[r] + (float)xv[2];
                float go = acc3[r] + (float)xv[3];
                float ii = sigmoid_f(gi);
                float ff = sigmoid_f(gf);
                float gt = tanh_f(gg);
                float oo = sigmoid_f(go);
                int ci = row * LDC + col;
                float cn = ff * cbuf[ci] + ii * gt;
                cbuf[ci] = cn;
                float hh = oo * tanh_f(cn);
                hn[row * LDA + col] = (f16)hh;
                if (t == lens[row] - 1) {
                    float s0 = hh * Wc[col];
                    float s1 = hh * Wc[GP + col];
                    s0 += __shfl_xor(s0, 1); s1 += __shfl_xor(s1, 1);
                    s0 += __shfl_xor(s0, 2); s1 += __shfl_xor(s1, 2);
                    s0 += __shfl_xor(s0, 4); s1 += __shfl_xor(s1, 4);
                    s0 += __shfl_xor(s0, 8); s1 += __shfl_xor(s1, 8);
                    if (c == 0) {
                        if (wave == 0 && nt == 0) { s0 += cls_b[0]; s1 += cls_b[1]; }
                        atomicAdd(out + (size_t)(b0 + row) * 2 + 0, s0);
                        atomicAdd(out + (size_t)(b0 + row) * 2 + 1, s1);
                    }
                }
            }
        }
        __syncthreads();
        cur ^= 1;
    }
}

// kR8 (fallback, proven): fused [h|x] recurrence for small-ws runs.
__global__ __launch_bounds__(512, 2)
void kR8(const int* __restrict__ cap,
         const int* __restrict__ cap_len,
         const f16* __restrict__ embT,
         const f16* __restrict__ Wpk,
         const float* __restrict__ biasp,
         float* __restrict__ hlast) {
    extern __shared__ __align__(16) char smem[];
    f16*   hbuf  = (f16*)smem;                          // 10496
    f16*   xbuf  = (f16*)(smem + 10496);                // 10496
    f16*   gates = (f16*)(smem + 20992);                // 39168
    float* biasL = (float*)(smem + 60160);              // 4864
    int*   capv  = (int*)(smem + 65024);                // 2048
    int*   lens  = (int*)(smem + 67072);                // 64
    int tid = threadIdx.x;
    int b0 = blockIdx.x * 16;
    if (tid < 16) lens[tid] = cap_len[b0 + tid];
    for (int i = tid; i < 16 * T_SZ; i += 512) capv[i] = cap[(size_t)b0 * T_SZ + i];
    for (int i = tid; i < 16 * LDA; i += 512) hbuf[i] = (f16)0.f;
    for (int i = tid; i < G4; i += 512) biasL[i] = biasp[i];
    __syncthreads();
    for (int i = tid; i < 16 * 40; i += 512) {
        int m = i / 40, c8 = i - m * 40;
        int v = capv[m * T_SZ + 0];
        *(f16x8*)(xbuf + m * LDA + c8 * 8) = *(const f16x8*)(embT + (size_t)v * KP + c8 * 8);
    }
    __syncthreads();
    int wave = tid >> 6, lane = tid & 63;
    int c = lane & 15, q = lane >> 4;
    int gate = wave >> 1, half = wave & 1;
    int nt0 = half * 10, ntiles = half ? 9 : 10;
    const f16* wp0 = Wpk + ((size_t)((gate * 19 + nt0) * 20) * 64 + lane) * 8;
    const f16* hrow = hbuf + c * LDA + q * 8;
    const f16* xrow = xbuf + c * LDA + q * 8;
    float creg[10];
#pragma unroll
    for (int i = 0; i < 10; ++i) creg[i] = 0.f;

    for (int t = 0; t < T_SZ; ++t) {
        f16x8 afr[10];
#pragma unroll
        for (int k = 0; k < 10; ++k)
            afr[k] = *(const f16x8*)(hrow + k * 32);
        f16x8 buf[10];
#pragma unroll
        for (int s = 0; s < 10; ++s)
            buf[s] = *(const f16x8*)(wp0 + (size_t)s * 512);
#pragma unroll 1
        for (int nt = 0; nt < ntiles - 1; ++nt) {
            int base = nt * 20;
            int ncol = gate * GP + (nt0 + nt) * 16 + c;
            float bia = biasL[ncol];
            f32x4 acch = {bia, bia, bia, bia};
            f32x4 accx = {0.f, 0.f, 0.f, 0.f};
#pragma unroll
            for (int k = 0; k < 20; ++k) {
                if (k < 10) {
                    acch = __builtin_amdgcn_mfma_f32_16x16x32_f16(afr[k], buf[k % 10], acch, 0, 0, 0);
                } else {
                    f16x8 a = *(const f16x8*)(xrow + (k - 10) * 32);
                    accx = __builtin_amdgcn_mfma_f32_16x16x32_f16(a, buf[k % 10], accx, 0, 0, 0);
                }
                buf[k % 10] = *(const f16x8*)(wp0 + (size_t)(base + k + 10) * 512);
            }
#pragma unroll
            for (int r = 0; r < 4; ++r)
                gates[(q * 4 + r) * LDG + ncol] = (f16)(acch[r] + accx[r]);
        }
        {
            int nt = ntiles - 1;
            int base = nt * 20;
            int ncol = gate * GP + (nt0 + nt) * 16 + c;
            float bia = biasL[ncol];
            f32x4 acch = {bia, bia, bia, bia};
            f32x4 accx = {0.f, 0.f, 0.f, 0.f};
#pragma unroll
            for (int k = 0; k < 20; ++k) {
                if (k < 10) {
                    acch = __builtin_amdgcn_mfma_f32_16x16x32_f16(afr[k], buf[k % 10], acch, 0, 0, 0);
                    buf[k % 10] = *(const f16x8*)(wp0 + (size_t)(base + k + 10) * 512);
                } else {
                    f16x8 a = *(const f16x8*)(xrow + (k - 10) * 32);
                    accx = __builtin_amdgcn_mfma_f32_16x16x32_f16(a, buf[k % 10], accx, 0, 0, 0);
                }
            }
#pragma unroll
            for (int r = 0; r < 4; ++r)
                gates[(q * 4 + r) * LDG + ncol] = (f16)(acch[r] + accx[r]);
        }
        __syncthreads();
        int tp1 = t + 1;
        if (tp1 < T_SZ) {
            for (int i = tid; i < 16 * 40; i += 512) {
                int m = i / 40, c8 = i - m * 40;
                int v = capv[m * T_SZ + tp1];
                *(f16x8*)(xbuf + m * LDA + c8 * 8) =
                    *(const f16x8*)(embT + (size_t)v * KP + c8 * 8);
            }
        }
#pragma unroll
        for (int it = 0; it < 10; ++it) {
            int idx = tid + it * 512;
            int m = idx / 320, j = idx - m * 320;
            if (j < H_SZ) {
                const f16* gr = gates + m * LDG;
                float gi = (float)gr[j];
                float gf = (float)gr[GP + j];
                float gg = (float)gr[2 * GP + j];
                float go = (float)gr[3 * GP + j];
                float ii = sigmoid_f(gi);
                float ff = sigmoid_f(gf);
                float gt = tanh_f(gg);
                float oo = sigmoid_f(go);
                float cn = ff * creg[it] + ii * gt;
                creg[it] = cn;
                float hh = oo * tanh_f(cn);
                hbuf[m * LDA + j] = (f16)hh;
                if (t == lens[m] - 1) hlast[(size_t)(b0 + m) * GP + j] = hh;
            }
        }
        __syncthreads();
    }
}

// kC: out[row][cl] = hlast[row] . Wc[cl] + cls_b[cl]   (fallback path only)
__global__ void kC(const float* __restrict__ hlast, const float* __restrict__ Wc,
                   const float* __restrict__ cls_b, float* __restrict__ out) {
    int row = blockIdx.x, lane = threadIdx.x;
    const float* h = hlast + (size_t)row * GP;
    float s0 = 0.f, s1 = 0.f;
    for (int j = lane; j < H_SZ; j += 64) {
        float hv = h[j];
        s0 += hv * Wc[j];
        s1 += hv * Wc[GP + j];
    }
    for (int off = 32; off; off >>= 1) {
        s0 += __shfl_down(s0, off);
        s1 += __shfl_down(s1, off);
    }
    if (lane == 0) {
        out[row * 2 + 0] = s0 + cls_b[0];
        out[row * 2 + 1] = s1 + cls_b[1];
    }
}

extern "C" void kernel_launch(void* const* d_in, const int* in_sizes, int n_in,
                              void* d_out, int out_size, void* d_ws, size_t ws_size,
                              hipStream_t stream) {
    const int*   cap     = (const int*)d_in[0];
    const int*   cap_len = (const int*)d_in[1];
    const float* embed_w = (const float*)d_in[2];
    const float* W_ih    = (const float*)d_in[3];
    const float* W_hh    = (const float*)d_in[4];
    const float* b_ih    = (const float*)d_in[5];
    const float* b_hh    = (const float*)d_in[6];
    const float* cls_v   = (const float*)d_in[7];
    const float* cls_g   = (const float*)d_in[8];
    const float* cls_b   = (const float*)d_in[9];
    float* out = (float*)d_out;

    char* w = (char*)d_ws;
    size_t off = 0;
    auto alloc = [&](size_t bytes) -> void* {
        void* p = w + off;
        off += (bytes + 255) & ~(size_t)255;
        return p;
    };
    f16*   embT  = (f16*)alloc((size_t)VOCAB * KP * sizeof(f16));      // 6.4 MB
    f16*   Wpk   = (f16*)alloc((size_t)1520 * 64 * 8 * sizeof(f16));   // 1.56 MB
    f16*   WgS   = (f16*)alloc((size_t)800 * 64 * 8 * sizeof(f16));    // 819 KB
    float* biasp = (float*)alloc((size_t)G4 * sizeof(float));
    float* Wc    = (float*)alloc((size_t)2 * GP * sizeof(float));
    float* hlast = (float*)alloc((size_t)B_SZ * GP * sizeof(float));   // 5.0 MB (fallback)
    f16*   embX  = (f16*)(w + off);                                    // 24.3 MB f16 [V][GP][4]
    size_t need_split = off + ((size_t)VOCAB * GP * 4 * sizeof(f16) + 255);
    bool split = (ws_size >= need_split);          // deterministic per run

    kP0<<<VOCAB, KP, 0, stream>>>(embed_w, embT);
    kPW2<<<1520, 64, 0, stream>>>(W_ih, W_hh, b_ih, b_hh, Wpk, biasp);
    kP2<<<1, 64, 0, stream>>>(cls_v, cls_g, Wc);
    if (split) {
        (void)hipMemsetAsync(out, 0, (size_t)out_size, stream);   // fused-kC accumulator
        kPW4<<<800, 64, 0, stream>>>(W_hh, WgS);
        kX2<<<VOCAB / 16, 512, 0, stream>>>(embT, Wpk, biasp, embX);
        static const int smem_r22 = 155648;
        (void)hipFuncSetAttribute((const void*)kR22,
                                  hipFuncAttributeMaxDynamicSharedMemorySize, smem_r22);
        kR22<<<NBLK, 512, smem_r22, stream>>>(cap, cap_len, embX, WgS, Wc, cls_b, out);
    } else {
        static const int smem_r8 = 67072 + 64;
        (void)hipFuncSetAttribute((const void*)kR8,
                                  hipFuncAttributeMaxDynamicSharedMemorySize, smem_r8);
        kR8<<<B_SZ / 16, 512, smem_r8, stream>>>(cap, cap_len, embT, Wpk, biasp, hlast);
        kC<<<B_SZ, 64, 0, stream>>>(hlast, Wc, cls_b, out);
    }
}